// Round 1
// baseline (1166.676 us; speedup 1.0000x reference)
//
#include <hip/hip_runtime.h>
#include <math.h>

// Problem constants
#define B_   4
#define C_   256
#define T_   8
#define HW_  1024
#define PM_  (T_ * HW_)   // 8192 positions per (b,c) for motion
#define PR_  HW_          // 1024 positions per (b,c) for ref
#define NM_  (C_ * PM_)   // 2,097,152 elements per motion sample
#define NR_  (C_ * PR_)   // 262,144 elements per ref sample
#define NBM  128          // stats blocks per motion sample
#define NBR  16           // stats blocks per ref sample
#define EPS_ 1e-6f

// ---------------------------------------------------------------------------
// Kernel 1: GroupNorm partial sums (sum, sumsq) per block chunk, deterministic
// ---------------------------------------------------------------------------
__global__ __launch_bounds__(256) void gn_stats(const float* __restrict__ x,
                                                int per_sample, int nblk,
                                                float* __restrict__ part) {
    int b   = blockIdx.x / nblk;
    int blk = blockIdx.x % nblk;
    const float* xb = x + (size_t)b * per_sample;
    int chunk = per_sample / nblk;   // divisible by construction
    int base  = blk * chunk;
    float s = 0.f, s2 = 0.f;
    for (int i = threadIdx.x * 4; i < chunk; i += 256 * 4) {
        float4 v = *(const float4*)(xb + base + i);
        s  += v.x + v.y + v.z + v.w;
        s2 += v.x * v.x + v.y * v.y + v.z * v.z + v.w * v.w;
    }
    // wave (64-lane) reduce
    #pragma unroll
    for (int off = 32; off; off >>= 1) {
        s  += __shfl_down(s, off);
        s2 += __shfl_down(s2, off);
    }
    __shared__ float red[8];
    int wid = threadIdx.x >> 6, lane = threadIdx.x & 63;
    if (lane == 0) { red[wid * 2] = s; red[wid * 2 + 1] = s2; }
    __syncthreads();
    if (threadIdx.x == 0) {
        for (int w = 1; w < 4; ++w) { s += red[w * 2]; s2 += red[w * 2 + 1]; }
        part[(size_t)(b * nblk + blk) * 2]     = s;
        part[(size_t)(b * nblk + blk) * 2 + 1] = s2;
    }
}

// ---------------------------------------------------------------------------
// Kernel 2: finalize GN -> per (b,c) affine  h = x*alpha + delta
//   alpha = rstd*gamma[c],  delta = beta[c] - mu*rstd*gamma[c]
// ---------------------------------------------------------------------------
__global__ __launch_bounds__(256) void gn_finalize(const float* __restrict__ part_m,
                                                   const float* __restrict__ part_r,
                                                   const float* __restrict__ gamma,
                                                   const float* __restrict__ beta,
                                                   float* __restrict__ am, float* __restrict__ dm,
                                                   float* __restrict__ ar, float* __restrict__ dr) {
    int c = threadIdx.x;
    float g = gamma[c], be = beta[c];
    for (int b = 0; b < B_; ++b) {
        float s = 0.f, s2 = 0.f;
        for (int i = 0; i < NBM; ++i) { s += part_m[(b * NBM + i) * 2]; s2 += part_m[(b * NBM + i) * 2 + 1]; }
        float mu   = s / (float)NM_;
        float var  = s2 / (float)NM_ - mu * mu;
        float rstd = rsqrtf(var + EPS_);
        am[b * C_ + c] = rstd * g;
        dm[b * C_ + c] = be - mu * rstd * g;

        s = 0.f; s2 = 0.f;
        for (int i = 0; i < NBR; ++i) { s += part_r[(b * NBR + i) * 2]; s2 += part_r[(b * NBR + i) * 2 + 1]; }
        mu   = s / (float)NR_;
        var  = s2 / (float)NR_ - mu * mu;
        rstd = rsqrtf(var + EPS_);
        ar[b * C_ + c] = rstd * g;
        dr[b * C_ + c] = be - mu * rstd * g;
    }
}

// ---------------------------------------------------------------------------
// Kernel 3: 1x1 conv as GEMM.  Y[b][o][p] = bias[o] + sum_c W[o][c]*(X[b][c][p]*a+d)
// Tile: 128 pos x 64 out, K-tile 32. 256 threads, micro 4o x 8p (two f4 halves
// at p=tx*4 and p=64+tx*4 -> conflict-free ds_read_b128).
// Optional residual add (final conv writes d_out = x_motion + conv(attn_out)).
// ---------------------------------------------------------------------------
__global__ __launch_bounds__(256) void conv1x1(const float* __restrict__ X,
                                               const float* __restrict__ W,
                                               const float* __restrict__ bias,
                                               const float* __restrict__ alpha,
                                               const float* __restrict__ delta,
                                               const float* __restrict__ resid,
                                               float* __restrict__ Y,
                                               int P) {
    __shared__ float Xs[32][132];   // stride 132: 16B aligned rows, 2-way max on reads
    __shared__ float Ws[64][33];    // scalar broadcast reads, conflict-free
    int b  = blockIdx.z;
    int p0 = blockIdx.x * 128;
    int o0 = blockIdx.y * 64;
    int tid = threadIdx.x;
    int tx = tid & 15, ty = tid >> 4;
    const float* Xb = X + (size_t)b * C_ * P;

    float acc[4][8] = {};
    for (int c0 = 0; c0 < C_; c0 += 32) {
        // stage X tile (normalized): 32 x 128 = 1024 float4, 4 per thread
        #pragma unroll
        for (int pass = 0; pass < 4; ++pass) {
            int i = pass * 256 + tid;
            int r = i >> 5;        // row 0..31
            int f = i & 31;        // f4 col 0..31
            int c = c0 + r;
            float4 v = *(const float4*)(Xb + (size_t)c * P + p0 + f * 4);
            float a = 1.f, d = 0.f;
            if (alpha) { a = alpha[b * C_ + c]; d = delta[b * C_ + c]; }
            v.x = v.x * a + d; v.y = v.y * a + d; v.z = v.z * a + d; v.w = v.w * a + d;
            *(float4*)&Xs[r][f * 4] = v;
        }
        // stage W tile: 64 x 32 = 512 float4, 2 per thread
        #pragma unroll
        for (int pass = 0; pass < 2; ++pass) {
            int i = pass * 256 + tid;
            int o = i >> 3;        // 0..63
            int f = i & 7;
            float4 v = *(const float4*)(W + (size_t)(o0 + o) * C_ + c0 + f * 4);
            Ws[o][f * 4 + 0] = v.x; Ws[o][f * 4 + 1] = v.y;
            Ws[o][f * 4 + 2] = v.z; Ws[o][f * 4 + 3] = v.w;
        }
        __syncthreads();
        #pragma unroll
        for (int kk = 0; kk < 32; ++kk) {
            float4 a0 = *(const float4*)&Xs[kk][tx * 4];
            float4 a1 = *(const float4*)&Xs[kk][64 + tx * 4];
            float w[4];
            #pragma unroll
            for (int i = 0; i < 4; ++i) w[i] = Ws[ty * 4 + i][kk];
            #pragma unroll
            for (int i = 0; i < 4; ++i) {
                acc[i][0] += w[i] * a0.x; acc[i][1] += w[i] * a0.y;
                acc[i][2] += w[i] * a0.z; acc[i][3] += w[i] * a0.w;
                acc[i][4] += w[i] * a1.x; acc[i][5] += w[i] * a1.y;
                acc[i][6] += w[i] * a1.z; acc[i][7] += w[i] * a1.w;
            }
        }
        __syncthreads();
    }
    // epilogue
    #pragma unroll
    for (int i = 0; i < 4; ++i) {
        int o = o0 + ty * 4 + i;
        float bo_ = bias[o];
        size_t rowb = ((size_t)b * C_ + o) * P + p0;
        #pragma unroll
        for (int half = 0; half < 2; ++half) {
            int pp = half * 64 + tx * 4;
            float4 r;
            r.x = acc[i][half * 4 + 0] + bo_;
            r.y = acc[i][half * 4 + 1] + bo_;
            r.z = acc[i][half * 4 + 2] + bo_;
            r.w = acc[i][half * 4 + 3] + bo_;
            if (resid) {
                float4 rv = *(const float4*)(resid + rowb + pp);
                r.x += rv.x; r.y += rv.y; r.z += rv.z; r.w += rv.w;
            }
            *(float4*)(Y + rowb + pp) = r;
        }
    }
}

// ---------------------------------------------------------------------------
// Kernel 4: flash-style cross attention per (b, t, q-tile of 64).
// Q-tile (scaled by c^-0.5) resident in LDS [256c][64q]; K streamed in
// 32c x 64k sub-tiles; online softmax over 16 k-tiles; PV accumulated with
// V streamed in 64c x 64k chunks. acc[4 q][16 c] per thread, c = cc*16+tx.
// ---------------------------------------------------------------------------
__global__ __launch_bounds__(256) void cross_attn(const float* __restrict__ Q,  // [B][C][PM_]
                                                  const float* __restrict__ K,  // [B][C][PR_]
                                                  const float* __restrict__ V,  // [B][C][PR_]
                                                  float* __restrict__ O) {      // [B][C][PM_]
    __shared__ float Qs[256][64];   // 64 KB, reused as O-staging in epilogue
    __shared__ float Ks[32][64];    // 8 KB
    __shared__ float Ps[64][68];    // 17 KB, stride 68 -> conflict-free
    __shared__ float Vs[64][68];    // 17 KB

    int b = blockIdx.z, t = blockIdx.y;
    int q0 = blockIdx.x * 64;
    int tid = threadIdx.x;
    int tx = tid & 15, ty = tid >> 4;

    const float* Qb = Q + ((size_t)b * C_) * PM_ + t * HW_ + q0;
    const float* Kb = K + ((size_t)b * C_) * PR_;
    const float* Vb = V + ((size_t)b * C_) * PR_;

    // load Q tile, pre-scaled by 1/sqrt(C)=1/16
    #pragma unroll
    for (int pass = 0; pass < 16; ++pass) {
        int i = pass * 256 + tid;
        int c = i >> 4, f = i & 15;
        float4 v = *(const float4*)(Qb + (size_t)c * PM_ + f * 4);
        v.x *= 0.0625f; v.y *= 0.0625f; v.z *= 0.0625f; v.w *= 0.0625f;
        *(float4*)&Qs[c][f * 4] = v;
    }

    float m[4], l[4], acc[4][16];
    #pragma unroll
    for (int i = 0; i < 4; ++i) { m[i] = -INFINITY; l[i] = 0.f; }
    #pragma unroll
    for (int i = 0; i < 4; ++i)
        #pragma unroll
        for (int cc = 0; cc < 16; ++cc) acc[i][cc] = 0.f;
    __syncthreads();

    for (int kt = 0; kt < 16; ++kt) {
        int k0 = kt * 64;
        float s[4][4] = {};
        // ---- S = (Q^T K) tile, reduction over 256 c in 8 sub-tiles ----
        for (int cs = 0; cs < 8; ++cs) {
            #pragma unroll
            for (int pass = 0; pass < 2; ++pass) {
                int i = pass * 256 + tid;
                int r = i >> 4, f = i & 15;
                *(float4*)&Ks[r][f * 4] =
                    *(const float4*)(Kb + (size_t)(cs * 32 + r) * PR_ + k0 + f * 4);
            }
            __syncthreads();
            #pragma unroll
            for (int kc = 0; kc < 32; ++kc) {
                float4 qv = *(const float4*)&Qs[cs * 32 + kc][ty * 4];
                float4 kv = *(const float4*)&Ks[kc][tx * 4];
                float qa[4] = {qv.x, qv.y, qv.z, qv.w};
                float ka[4] = {kv.x, kv.y, kv.z, kv.w};
                #pragma unroll
                for (int i = 0; i < 4; ++i)
                    #pragma unroll
                    for (int j = 0; j < 4; ++j) s[i][j] += qa[i] * ka[j];
            }
            __syncthreads();
        }
        // ---- online softmax (rows owned by 16-lane groups: shfl_xor 8..1) ----
        float pl[4][4];
        #pragma unroll
        for (int i = 0; i < 4; ++i) {
            float tm = fmaxf(fmaxf(s[i][0], s[i][1]), fmaxf(s[i][2], s[i][3]));
            #pragma unroll
            for (int off = 8; off; off >>= 1) tm = fmaxf(tm, __shfl_xor(tm, off));
            float mn = fmaxf(m[i], tm);
            float sc = __expf(m[i] - mn);
            float rs = 0.f;
            #pragma unroll
            for (int j = 0; j < 4; ++j) { float e = __expf(s[i][j] - mn); pl[i][j] = e; rs += e; }
            #pragma unroll
            for (int off = 8; off; off >>= 1) rs += __shfl_xor(rs, off);
            m[i] = mn;
            l[i] = l[i] * sc + rs;
            #pragma unroll
            for (int cc = 0; cc < 16; ++cc) acc[i][cc] *= sc;
        }
        // ---- publish P tile ----
        #pragma unroll
        for (int i = 0; i < 4; ++i)
            #pragma unroll
            for (int j = 0; j < 4; ++j) Ps[ty * 4 + i][tx * 4 + j] = pl[i][j];
        __syncthreads();
        // ---- O += P * V, V streamed in 4 chunks of 64 c rows ----
        #pragma unroll
        for (int ch = 0; ch < 4; ++ch) {
            #pragma unroll
            for (int pass = 0; pass < 4; ++pass) {
                int i = pass * 256 + tid;
                int r = i >> 4, f = i & 15;
                float4 v = *(const float4*)(Vb + (size_t)(ch * 64 + r) * PR_ + k0 + f * 4);
                *(float4*)&Vs[r][f * 4] = v;
            }
            __syncthreads();
            #pragma unroll
            for (int kk = 0; kk < 64; ++kk) {
                float pv[4], vv[4];
                #pragma unroll
                for (int i = 0; i < 4; ++i) pv[i] = Ps[ty * 4 + i][kk];
                #pragma unroll
                for (int j = 0; j < 4; ++j) vv[j] = Vs[j * 16 + tx][kk];
                #pragma unroll
                for (int i = 0; i < 4; ++i)
                    #pragma unroll
                    for (int j = 0; j < 4; ++j) acc[i][ch * 4 + j] += pv[i] * vv[j];
            }
            __syncthreads();
        }
    }
    // ---- epilogue: normalize by l, stage into Qs as [c][q], coalesced store ----
    #pragma unroll
    for (int i = 0; i < 4; ++i) {
        float inv = 1.f / l[i];
        #pragma unroll
        for (int cc = 0; cc < 16; ++cc)
            Qs[cc * 16 + tx][ty * 4 + i] = acc[i][cc] * inv;
    }
    __syncthreads();
    float* Ob = O + ((size_t)b * C_) * PM_ + t * HW_ + q0;
    #pragma unroll
    for (int pass = 0; pass < 16; ++pass) {
        int i = pass * 256 + tid;
        int c = i >> 4, f = i & 15;
        *(float4*)(Ob + (size_t)c * PM_ + f * 4) = *(const float4*)&Qs[c][f * 4];
    }
}

// ---------------------------------------------------------------------------
// Launcher. ws usage (floats):
//   [0,1024)    motion partials   [1024,1152) ref partials
//   [2048,3072) alpha_m  [3072,4096) delta_m  [4096,5120) alpha_r  [5120,6144) delta_r
//   [8192, +8388608) q   then k (1048576), v (1048576), attn_out (8388608)
//   total ~75.5 MB
// ---------------------------------------------------------------------------
extern "C" void kernel_launch(void* const* d_in, const int* in_sizes, int n_in,
                              void* d_out, int out_size, void* d_ws, size_t ws_size,
                              hipStream_t stream) {
    const float* x_motion = (const float*)d_in[0];
    const float* x_ref    = (const float*)d_in[1];
    const float* gamma    = (const float*)d_in[2];
    const float* beta     = (const float*)d_in[3];
    const float* Wq = (const float*)d_in[4];
    const float* bq = (const float*)d_in[5];
    const float* Wk = (const float*)d_in[6];
    const float* bk = (const float*)d_in[7];
    const float* Wv = (const float*)d_in[8];
    const float* bv = (const float*)d_in[9];
    const float* Wo = (const float*)d_in[10];
    const float* bo = (const float*)d_in[11];
    float* out = (float*)d_out;
    float* ws  = (float*)d_ws;

    float* part_m = ws;
    float* part_r = ws + 1024;
    float* am = ws + 2048;
    float* dm = ws + 3072;
    float* ar = ws + 4096;
    float* dr = ws + 5120;
    float* q  = ws + 8192;
    float* k  = q + (size_t)B_ * C_ * PM_;
    float* v  = k + (size_t)B_ * C_ * PR_;
    float* ao = v + (size_t)B_ * C_ * PR_;

    gn_stats<<<dim3(B_ * NBM), 256, 0, stream>>>(x_motion, NM_, NBM, part_m);
    gn_stats<<<dim3(B_ * NBR), 256, 0, stream>>>(x_ref, NR_, NBR, part_r);
    gn_finalize<<<dim3(1), 256, 0, stream>>>(part_m, part_r, gamma, beta, am, dm, ar, dr);

    conv1x1<<<dim3(PM_ / 128, C_ / 64, B_), 256, 0, stream>>>(x_motion, Wq, bq, am, dm, nullptr, q, PM_);
    conv1x1<<<dim3(PR_ / 128, C_ / 64, B_), 256, 0, stream>>>(x_ref, Wk, bk, ar, dr, nullptr, k, PR_);
    conv1x1<<<dim3(PR_ / 128, C_ / 64, B_), 256, 0, stream>>>(x_ref, Wv, bv, ar, dr, nullptr, v, PR_);

    cross_attn<<<dim3(16, T_, B_), 256, 0, stream>>>(q, k, v, ao);

    conv1x1<<<dim3(PM_ / 128, C_ / 64, B_), 256, 0, stream>>>(ao, Wo, bo, nullptr, nullptr, x_motion, out, PM_);
}

// Round 2
// 325.764 us; speedup vs baseline: 3.5814x; 3.5814x over previous
//
#include <hip/hip_runtime.h>
#include <math.h>
#include <stdint.h>

// Problem constants
#define B_   4
#define C_   256
#define T_   8
#define HW_  1024
#define PM_  (T_ * HW_)   // 8192 positions per (b,c) for motion
#define PR_  HW_          // 1024 positions per (b,c) for ref
#define NM_  (C_ * PM_)
#define NR_  (C_ * PR_)
#define NBM  128
#define NBR  16
#define EPS_ 1e-6f

typedef unsigned short u16;
typedef __attribute__((ext_vector_type(8))) short short8;  // 8 bf16 = 4 VGPR
typedef __attribute__((ext_vector_type(4))) float f32x4;

__device__ inline u16 f2bf(float f) {                 // RNE f32->bf16
    uint32_t u = __builtin_bit_cast(uint32_t, f);
    u += 0x7fffu + ((u >> 16) & 1u);
    return (u16)(u >> 16);
}
__device__ inline uint32_t pk2bf(float a, float b) {
    return (uint32_t)f2bf(a) | ((uint32_t)f2bf(b) << 16);
}
__device__ inline float bfl(uint32_t u) { return __builtin_bit_cast(float, u << 16); }
__device__ inline float bfh(uint32_t u) { return __builtin_bit_cast(float, u & 0xffff0000u); }

// MFMA via inline asm: avoids builtin operand-type (short8 vs bf16x8) ambiguity.
__device__ inline f32x4 mfma16(short8 a, short8 b, f32x4 c) {
    f32x4 d;
    asm("v_mfma_f32_16x16x32_bf16 %0, %1, %2, %3" : "=v"(d) : "v"(a), "v"(b), "0"(c));
    return d;
}

// ---------------------------------------------------------------------------
// Kernel 1: GroupNorm partial sums (deterministic two-stage)
// ---------------------------------------------------------------------------
__global__ __launch_bounds__(256) void gn_stats(const float* __restrict__ x,
                                                int per_sample, int nblk,
                                                float* __restrict__ part) {
    int b   = blockIdx.x / nblk;
    int blk = blockIdx.x % nblk;
    const float* xb = x + (size_t)b * per_sample;
    int chunk = per_sample / nblk;
    int base  = blk * chunk;
    float s = 0.f, s2 = 0.f;
    for (int i = threadIdx.x * 4; i < chunk; i += 256 * 4) {
        float4 v = *(const float4*)(xb + base + i);
        s  += v.x + v.y + v.z + v.w;
        s2 += v.x * v.x + v.y * v.y + v.z * v.z + v.w * v.w;
    }
    #pragma unroll
    for (int off = 32; off; off >>= 1) {
        s  += __shfl_down(s, off);
        s2 += __shfl_down(s2, off);
    }
    __shared__ float red[8];
    int wid = threadIdx.x >> 6, lane = threadIdx.x & 63;
    if (lane == 0) { red[wid * 2] = s; red[wid * 2 + 1] = s2; }
    __syncthreads();
    if (threadIdx.x == 0) {
        for (int w = 1; w < 4; ++w) { s += red[w * 2]; s2 += red[w * 2 + 1]; }
        part[(size_t)(b * nblk + blk) * 2]     = s;
        part[(size_t)(b * nblk + blk) * 2 + 1] = s2;
    }
}

// ---------------------------------------------------------------------------
// Kernel 2: finalize GN -> per (b,c) affine
// ---------------------------------------------------------------------------
__global__ __launch_bounds__(256) void gn_finalize(const float* __restrict__ part_m,
                                                   const float* __restrict__ part_r,
                                                   const float* __restrict__ gamma,
                                                   const float* __restrict__ beta,
                                                   float* __restrict__ am, float* __restrict__ dm,
                                                   float* __restrict__ ar, float* __restrict__ dr) {
    int c = threadIdx.x;
    float g = gamma[c], be = beta[c];
    for (int b = 0; b < B_; ++b) {
        float s = 0.f, s2 = 0.f;
        for (int i = 0; i < NBM; ++i) { s += part_m[(b * NBM + i) * 2]; s2 += part_m[(b * NBM + i) * 2 + 1]; }
        float mu   = s / (float)NM_;
        float var  = s2 / (float)NM_ - mu * mu;
        float rstd = rsqrtf(var + EPS_);
        am[b * C_ + c] = rstd * g;
        dm[b * C_ + c] = be - mu * rstd * g;

        s = 0.f; s2 = 0.f;
        for (int i = 0; i < NBR; ++i) { s += part_r[(b * NBR + i) * 2]; s2 += part_r[(b * NBR + i) * 2 + 1]; }
        mu   = s / (float)NR_;
        var  = s2 / (float)NR_ - mu * mu;
        rstd = rsqrtf(var + EPS_);
        ar[b * C_ + c] = rstd * g;
        dr[b * C_ + c] = be - mu * rstd * g;
    }
}

// ---------------------------------------------------------------------------
// Kernel 3: 1x1 conv as GEMM (fp32 micro-kernel).
// IN:  0 = f32 X [b][c][p] (+ optional GN affine), 1 = bf16 X [b][c][p]
// OUT: 0 = f32 [b][c][p] (+ optional resid), 1 = bf16 [b][c][p],
//      2 = bf16 TRANSPOSED [b][p][c]   (for Q^T / K^T; oscale folds c^-0.5)
// ---------------------------------------------------------------------------
template<int IN, int OUT>
__global__ __launch_bounds__(256) void conv1x1(const void* __restrict__ Xv,
                                               const float* __restrict__ W,
                                               const float* __restrict__ bias,
                                               const float* __restrict__ alpha,
                                               const float* __restrict__ delta,
                                               const float* __restrict__ resid,
                                               void* __restrict__ Yv,
                                               int P, float oscale) {
    __shared__ float Xs[32][132];
    __shared__ float Ws[64][33];
    int b  = blockIdx.z;
    int p0 = blockIdx.x * 128;
    int o0 = blockIdx.y * 64;
    int tid = threadIdx.x;
    int tx = tid & 15, ty = tid >> 4;

    float acc[4][8] = {};
    for (int c0 = 0; c0 < C_; c0 += 32) {
        if constexpr (IN == 0) {
            const float* Xb = (const float*)Xv + (size_t)b * C_ * P;
            #pragma unroll
            for (int pass = 0; pass < 4; ++pass) {
                int i = pass * 256 + tid;
                int r = i >> 5, f = i & 31;
                int c = c0 + r;
                float4 v = *(const float4*)(Xb + (size_t)c * P + p0 + f * 4);
                float a = alpha ? alpha[b * C_ + c] : 1.f;
                float d = alpha ? delta[b * C_ + c] : 0.f;
                v.x = v.x * a + d; v.y = v.y * a + d; v.z = v.z * a + d; v.w = v.w * a + d;
                *(float4*)&Xs[r][f * 4] = v;
            }
        } else {
            const u16* Xb = (const u16*)Xv + (size_t)b * C_ * P;
            #pragma unroll
            for (int pass = 0; pass < 2; ++pass) {
                int i = pass * 256 + tid;
                int r = i >> 4, f = i & 15;   // 16B chunk = 8 bf16
                uint4 d = *(const uint4*)(Xb + (size_t)(c0 + r) * P + p0 + f * 8);
                float* xr = &Xs[r][f * 8];
                xr[0] = bfl(d.x); xr[1] = bfh(d.x); xr[2] = bfl(d.y); xr[3] = bfh(d.y);
                xr[4] = bfl(d.z); xr[5] = bfh(d.z); xr[6] = bfl(d.w); xr[7] = bfh(d.w);
            }
        }
        #pragma unroll
        for (int pass = 0; pass < 2; ++pass) {
            int i = pass * 256 + tid;
            int o = i >> 3, f = i & 7;
            float4 v = *(const float4*)(W + (size_t)(o0 + o) * C_ + c0 + f * 4);
            Ws[o][f * 4 + 0] = v.x; Ws[o][f * 4 + 1] = v.y;
            Ws[o][f * 4 + 2] = v.z; Ws[o][f * 4 + 3] = v.w;
        }
        __syncthreads();
        #pragma unroll
        for (int kk = 0; kk < 32; ++kk) {
            float4 a0 = *(const float4*)&Xs[kk][tx * 4];
            float4 a1 = *(const float4*)&Xs[kk][64 + tx * 4];
            float wv[4];
            #pragma unroll
            for (int i = 0; i < 4; ++i) wv[i] = Ws[ty * 4 + i][kk];
            #pragma unroll
            for (int i = 0; i < 4; ++i) {
                acc[i][0] += wv[i] * a0.x; acc[i][1] += wv[i] * a0.y;
                acc[i][2] += wv[i] * a0.z; acc[i][3] += wv[i] * a0.w;
                acc[i][4] += wv[i] * a1.x; acc[i][5] += wv[i] * a1.y;
                acc[i][6] += wv[i] * a1.z; acc[i][7] += wv[i] * a1.w;
            }
        }
        __syncthreads();
    }
    float bo_[4];
    #pragma unroll
    for (int i = 0; i < 4; ++i) bo_[i] = bias[o0 + ty * 4 + i];

    if constexpr (OUT == 0) {
        float* Y = (float*)Yv;
        #pragma unroll
        for (int i = 0; i < 4; ++i) {
            size_t rowb = ((size_t)b * C_ + o0 + ty * 4 + i) * P + p0;
            #pragma unroll
            for (int half = 0; half < 2; ++half) {
                int pp = half * 64 + tx * 4;
                float4 r;
                r.x = acc[i][half * 4 + 0] + bo_[i];
                r.y = acc[i][half * 4 + 1] + bo_[i];
                r.z = acc[i][half * 4 + 2] + bo_[i];
                r.w = acc[i][half * 4 + 3] + bo_[i];
                if (resid) {
                    float4 rv = *(const float4*)(resid + rowb + pp);
                    r.x += rv.x; r.y += rv.y; r.z += rv.z; r.w += rv.w;
                }
                *(float4*)(Y + rowb + pp) = r;
            }
        }
    } else if constexpr (OUT == 1) {
        u16* Y = (u16*)Yv;
        #pragma unroll
        for (int i = 0; i < 4; ++i) {
            size_t rowb = ((size_t)b * C_ + o0 + ty * 4 + i) * P + p0;
            #pragma unroll
            for (int half = 0; half < 2; ++half) {
                int pp = half * 64 + tx * 4;
                ushort4 pk;
                pk.x = f2bf((acc[i][half * 4 + 0] + bo_[i]) * oscale);
                pk.y = f2bf((acc[i][half * 4 + 1] + bo_[i]) * oscale);
                pk.z = f2bf((acc[i][half * 4 + 2] + bo_[i]) * oscale);
                pk.w = f2bf((acc[i][half * 4 + 3] + bo_[i]) * oscale);
                *(ushort4*)(Y + rowb + pp) = pk;
            }
        }
    } else {
        u16* Y = (u16*)Yv;
        #pragma unroll
        for (int half = 0; half < 2; ++half)
            #pragma unroll
            for (int j = 0; j < 4; ++j) {
                int p = p0 + half * 64 + tx * 4 + j;
                ushort4 pk;
                pk.x = f2bf((acc[0][half * 4 + j] + bo_[0]) * oscale);
                pk.y = f2bf((acc[1][half * 4 + j] + bo_[1]) * oscale);
                pk.z = f2bf((acc[2][half * 4 + j] + bo_[2]) * oscale);
                pk.w = f2bf((acc[3][half * 4 + j] + bo_[3]) * oscale);
                *(ushort4*)(Y + ((size_t)b * P + p) * C_ + o0 + ty * 4) = pk;
            }
    }
}

// ---------------------------------------------------------------------------
// Kernel 4: MFMA flash cross-attention.
// Block = (b, t, 64-q tile), 4 waves x 16 q. Q^T [b][p][c] frags in regs;
// K^T [b][k][c] tile + V [b][c][k] tile staged to XOR-swizzled LDS.
// S^T = mfma(K,Q): row k=(lg*4+reg), col q=ln  [verified C/D map].
// Online softmax keyed by q=ln; P via swizzled per-wave LDS; PV -> acc f32.
// ---------------------------------------------------------------------------
__global__ __launch_bounds__(256) void attn_mfma(const u16* __restrict__ qT,
                                                 const u16* __restrict__ kT,
                                                 const u16* __restrict__ vh,
                                                 u16* __restrict__ ao) {
    __shared__ u16 Ks[64 * 256];   // [k][c] swizzled, 32 KB
    __shared__ u16 Vs[256 * 64];   // [c][k] swizzled, 32 KB (reused for O in epilogue)
    __shared__ u16 Ps[4][16 * 64]; // per-wave P [q][k] swizzled, 2 KB each

    int b = blockIdx.z, t = blockIdx.y;
    int q0 = blockIdx.x * 64;
    int tid = threadIdx.x;
    int w = tid >> 6, l = tid & 63;
    int lg = l >> 4, ln = l & 15;

    // Q fragments (B operand), resident for whole kernel
    const u16* Qrow = qT + ((size_t)b * PM_ + (size_t)t * HW_ + q0 + w * 16 + ln) * C_;
    short8 qf[8];
    #pragma unroll
    for (int f = 0; f < 8; ++f)
        qf[f] = __builtin_bit_cast(short8, *(const uint4*)(Qrow + f * 32 + lg * 8));

    f32x4 acc[16];
    #pragma unroll
    for (int cc = 0; cc < 16; ++cc) acc[cc] = (f32x4)0.f;
    float m_r = -1e30f, l_r = 0.f;

    const u16* Kb = kT + (size_t)b * PR_ * C_;
    const u16* Vb = vh + (size_t)b * C_ * PR_;
    u16* pw = &Ps[w][0];

    for (int kt = 0; kt < 16; ++kt) {
        int k0 = kt * 64;
        // ---- stage K^T tile (contiguous 32 KB) and V tile ----
        const char* Ktile = (const char*)(Kb + (size_t)k0 * C_);
        #pragma unroll
        for (int p = 0; p < 8; ++p) {
            int off = (p * 256 + tid) * 16;
            int sw  = ((off >> 9) & 7) << 4;
            *(uint4*)((char*)Ks + (off ^ sw)) = *(const uint4*)(Ktile + off);
        }
        #pragma unroll
        for (int p = 0; p < 8; ++p) {
            int i = p * 256 + tid;
            int c = i >> 3, s = i & 7;
            uint4 d = *(const uint4*)(Vb + (size_t)c * PR_ + k0 + s * 8);
            int off = c * 128 + s * 16;
            *(uint4*)((char*)Vs + (off ^ ((c & 7) << 4))) = d;
        }
        __syncthreads();

        // ---- S^T = K · Q ----
        f32x4 sacc[4];
        #pragma unroll
        for (int j = 0; j < 4; ++j) sacc[j] = (f32x4)0.f;
        #pragma unroll
        for (int f = 0; f < 8; ++f) {
            #pragma unroll
            for (int j = 0; j < 4; ++j) {
                int krow = j * 16 + ln;
                int byteo = krow * 512 + ((f * 64 + lg * 16) ^ ((krow & 7) << 4));
                short8 kf = __builtin_bit_cast(short8, *(const uint4*)((const char*)Ks + byteo));
                sacc[j] = mfma16(kf, qf[f], sacc[j]);
            }
        }

        // ---- online softmax (state keyed by q = ln) ----
        float tm = -1e30f;
        #pragma unroll
        for (int j = 0; j < 4; ++j)
            #pragma unroll
            for (int r = 0; r < 4; ++r) tm = fmaxf(tm, sacc[j][r]);
        tm = fmaxf(tm, __shfl_xor(tm, 16));
        tm = fmaxf(tm, __shfl_xor(tm, 32));
        float mn = fmaxf(m_r, tm);
        float sc = __expf(m_r - mn);
        float rs = 0.f;
        float pv[4][4];
        #pragma unroll
        for (int j = 0; j < 4; ++j)
            #pragma unroll
            for (int r = 0; r < 4; ++r) { float e = __expf(sacc[j][r] - mn); pv[j][r] = e; rs += e; }
        rs += __shfl_xor(rs, 16);
        rs += __shfl_xor(rs, 32);
        m_r = mn;
        l_r = l_r * sc + rs;
        // publish P rows q=ln (k = 16j + 4lg + r)
        #pragma unroll
        for (int j = 0; j < 4; ++j) {
            int addr = ln * 128 + ((j * 32 + lg * 8) ^ ((ln & 7) << 4));
            *(uint32_t*)((char*)pw + addr)     = pk2bf(pv[j][0], pv[j][1]);
            *(uint32_t*)((char*)pw + addr + 4) = pk2bf(pv[j][2], pv[j][3]);
        }

        // rescale acc (acc rows are q = 4*lg + r -> fetch that q's scale)
        float scr[4];
        #pragma unroll
        for (int r = 0; r < 4; ++r) scr[r] = __shfl(sc, (lg << 4) + lg * 4 + r);
        #pragma unroll
        for (int cc = 0; cc < 16; ++cc)
            #pragma unroll
            for (int r = 0; r < 4; ++r) acc[cc][r] *= scr[r];

        // ---- O += P · V ----
        #pragma unroll
        for (int ks = 0; ks < 2; ++ks) {
            int pb = ln * 128 + ((ks * 64 + lg * 16) ^ ((ln & 7) << 4));
            short8 pf = __builtin_bit_cast(short8, *(const uint4*)((const char*)pw + pb));
            #pragma unroll
            for (int cc = 0; cc < 16; ++cc) {
                int c = cc * 16 + ln;
                int vb_ = c * 128 + ((ks * 64 + lg * 16) ^ ((c & 7) << 4));
                short8 vf = __builtin_bit_cast(short8, *(const uint4*)((const char*)Vs + vb_));
                acc[cc] = mfma16(pf, vf, acc[cc]);
            }
        }
        __syncthreads();
    }

    // ---- epilogue: O/l -> bf16, stage [c][64q] swizzled in Vs, coalesced out ----
    float invl = 1.f / l_r;
    float invr[4];
    #pragma unroll
    for (int r = 0; r < 4; ++r) invr[r] = __shfl(invl, (lg << 4) + lg * 4 + r);
    #pragma unroll
    for (int cc = 0; cc < 16; ++cc) {
        int c = cc * 16 + ln;
        int qb = w * 32 + lg * 8;   // byte col for q = w*16 + 4*lg (+r)
        int a0 = c * 128 + (qb ^ ((c & 7) << 4));
        *(uint32_t*)((char*)Vs + a0)     = pk2bf(acc[cc][0] * invr[0], acc[cc][1] * invr[1]);
        *(uint32_t*)((char*)Vs + a0 + 4) = pk2bf(acc[cc][2] * invr[2], acc[cc][3] * invr[3]);
    }
    __syncthreads();
    u16* aob = ao + (size_t)b * C_ * PM_ + (size_t)t * HW_ + q0;
    #pragma unroll
    for (int p = 0; p < 8; ++p) {
        int i = p * 256 + tid;
        int c = i >> 3, s = i & 7;
        int off = c * 128 + s * 16;
        uint4 d = *(const uint4*)((const char*)Vs + (off ^ ((c & 7) << 4)));
        *(uint4*)(aob + (size_t)c * PM_ + s * 8) = d;
    }
}

// ---------------------------------------------------------------------------
// Launcher. ws byte layout:
//   0       part_m (4 KB) | 4096 part_r | 8192 am | 12288 dm | 16384 ar | 20480 dr
//   32768   qT  bf16 [4][8192][256]  (16 MB)
//   +16MB   kT  bf16 [4][1024][256]  (2 MB)
//   +2MB    vh  bf16 [4][256][1024]  (2 MB)
//   +2MB    ao  bf16 [4][256][8192]  (16 MB)    total ~36 MB
// ---------------------------------------------------------------------------
extern "C" void kernel_launch(void* const* d_in, const int* in_sizes, int n_in,
                              void* d_out, int out_size, void* d_ws, size_t ws_size,
                              hipStream_t stream) {
    const float* x_motion = (const float*)d_in[0];
    const float* x_ref    = (const float*)d_in[1];
    const float* gamma    = (const float*)d_in[2];
    const float* beta     = (const float*)d_in[3];
    const float* Wq = (const float*)d_in[4];
    const float* bq = (const float*)d_in[5];
    const float* Wk = (const float*)d_in[6];
    const float* bk = (const float*)d_in[7];
    const float* Wv = (const float*)d_in[8];
    const float* bv = (const float*)d_in[9];
    const float* Wo = (const float*)d_in[10];
    const float* bo = (const float*)d_in[11];
    float* out = (float*)d_out;
    char* base = (char*)d_ws;

    float* part_m = (float*)(base);
    float* part_r = (float*)(base + 4096);
    float* am = (float*)(base + 8192);
    float* dm = (float*)(base + 12288);
    float* ar = (float*)(base + 16384);
    float* dr = (float*)(base + 20480);
    u16* qT  = (u16*)(base + 32768);
    u16* kTp = (u16*)(base + 32768 + 16777216);
    u16* vh  = (u16*)(base + 32768 + 16777216 + 2097152);
    u16* aoh = (u16*)(base + 32768 + 16777216 + 2 * 2097152);

    gn_stats<<<dim3(B_ * NBM), 256, 0, stream>>>(x_motion, NM_, NBM, part_m);
    gn_stats<<<dim3(B_ * NBR), 256, 0, stream>>>(x_ref, NR_, NBR, part_r);
    gn_finalize<<<dim3(1), 256, 0, stream>>>(part_m, part_r, gamma, beta, am, dm, ar, dr);

    // q: bf16 transposed [b][p][c], pre-scaled by c^-0.5 = 1/16 (exact in bf16)
    conv1x1<0, 2><<<dim3(PM_ / 128, C_ / 64, B_), 256, 0, stream>>>(
        x_motion, Wq, bq, am, dm, nullptr, qT, PM_, 0.0625f);
    // k: bf16 transposed [b][k][c]
    conv1x1<0, 2><<<dim3(PR_ / 128, C_ / 64, B_), 256, 0, stream>>>(
        x_ref, Wk, bk, ar, dr, nullptr, kTp, PR_, 1.f);
    // v: bf16 [b][c][k]
    conv1x1<0, 1><<<dim3(PR_ / 128, C_ / 64, B_), 256, 0, stream>>>(
        x_ref, Wv, bv, ar, dr, nullptr, vh, PR_, 1.f);

    attn_mfma<<<dim3(16, T_, B_), 256, 0, stream>>>(qT, kTp, vh, aoh);

    // final: bf16 in, fp32 out + residual
    conv1x1<1, 0><<<dim3(PM_ / 128, C_ / 64, B_), 256, 0, stream>>>(
        aoh, Wo, bo, nullptr, nullptr, x_motion, out, PM_, 1.f);
}

// Round 3
// 144.088 us; speedup vs baseline: 8.0970x; 2.2609x over previous
//
#include <hip/hip_runtime.h>
#include <math.h>
#include <stdint.h>

#define B_   4
#define C_   256
#define T_   8
#define HW_  1024
#define PM_  8192
#define PR_  1024
#define NM_  (C_ * PM_)
#define NR_  (C_ * PR_)
#define NBM  128
#define NBR  16
#define EPS_ 1e-6f

typedef unsigned short u16;
typedef unsigned int u32;
typedef __attribute__((ext_vector_type(8))) short short8;  // 8 bf16 = 4 VGPR
typedef __attribute__((ext_vector_type(4))) float f32x4;

__device__ inline u16 f2bf(float f) {                 // RNE f32->bf16
    uint32_t u = __builtin_bit_cast(uint32_t, f);
    u += 0x7fffu + ((u >> 16) & 1u);
    return (u16)(u >> 16);
}
__device__ inline u32 pk2bf(float a, float b) {
    return (u32)f2bf(a) | ((u32)f2bf(b) << 16);
}

__device__ inline f32x4 mfma16(short8 a, short8 b, f32x4 c) {
    f32x4 d;
    asm("v_mfma_f32_16x16x32_bf16 %0, %1, %2, %3" : "=v"(d) : "v"(a), "v"(b), "0"(c));
    return d;
}
__device__ __forceinline__ short8 lds8(const char* p) {
    return __builtin_bit_cast(short8, *(const uint4*)p);
}
// CK-style async global->LDS, 16B per lane. LDS dest = uniform base + lane*16
// (linear); swizzled layouts are achieved by pre-swizzling the per-lane
// global SOURCE address (inverse == same XOR, row-preserving).
__device__ __forceinline__ void gl16(const void* g, void* l) {
    __builtin_amdgcn_global_load_lds(
        reinterpret_cast<const uint32_t __attribute__((address_space(1)))*>(
            reinterpret_cast<uintptr_t>(g)),
        reinterpret_cast<uint32_t __attribute__((address_space(3)))*>(
            reinterpret_cast<uintptr_t>(l)),
        16, 0, 0);
}

// ---------------------------------------------------------------------------
// Kernel 1: GroupNorm partial sums (deterministic two-stage)
// ---------------------------------------------------------------------------
__global__ __launch_bounds__(256) void gn_stats(const float* __restrict__ x,
                                                int per_sample, int nblk,
                                                float* __restrict__ part) {
    int b   = blockIdx.x / nblk;
    int blk = blockIdx.x % nblk;
    const float* xb = x + (size_t)b * per_sample;
    int chunk = per_sample / nblk;
    int base  = blk * chunk;
    float s = 0.f, s2 = 0.f;
    for (int i = threadIdx.x * 4; i < chunk; i += 256 * 4) {
        float4 v = *(const float4*)(xb + base + i);
        s  += v.x + v.y + v.z + v.w;
        s2 += v.x * v.x + v.y * v.y + v.z * v.z + v.w * v.w;
    }
    #pragma unroll
    for (int off = 32; off; off >>= 1) {
        s  += __shfl_down(s, off);
        s2 += __shfl_down(s2, off);
    }
    __shared__ float red[8];
    int wid = threadIdx.x >> 6, lane = threadIdx.x & 63;
    if (lane == 0) { red[wid * 2] = s; red[wid * 2 + 1] = s2; }
    __syncthreads();
    if (threadIdx.x == 0) {
        for (int w = 1; w < 4; ++w) { s += red[w * 2]; s2 += red[w * 2 + 1]; }
        part[(size_t)(b * nblk + blk) * 2]     = s;
        part[(size_t)(b * nblk + blk) * 2 + 1] = s2;
    }
}

// ---------------------------------------------------------------------------
// Kernel 2: finalize GN -> per (b,c) affine
// ---------------------------------------------------------------------------
__global__ __launch_bounds__(256) void gn_finalize(const float* __restrict__ part_m,
                                                   const float* __restrict__ part_r,
                                                   const float* __restrict__ gamma,
                                                   const float* __restrict__ beta,
                                                   float* __restrict__ am, float* __restrict__ dm,
                                                   float* __restrict__ ar, float* __restrict__ dr) {
    int c = threadIdx.x;
    float g = gamma[c], be = beta[c];
    for (int b = 0; b < B_; ++b) {
        float s = 0.f, s2 = 0.f;
        for (int i = 0; i < NBM; ++i) { s += part_m[(b * NBM + i) * 2]; s2 += part_m[(b * NBM + i) * 2 + 1]; }
        float mu   = s / (float)NM_;
        float var  = s2 / (float)NM_ - mu * mu;
        float rstd = rsqrtf(var + EPS_);
        am[b * C_ + c] = rstd * g;
        dm[b * C_ + c] = be - mu * rstd * g;

        s = 0.f; s2 = 0.f;
        for (int i = 0; i < NBR; ++i) { s += part_r[(b * NBR + i) * 2]; s2 += part_r[(b * NBR + i) * 2 + 1]; }
        mu   = s / (float)NR_;
        var  = s2 / (float)NR_ - mu * mu;
        rstd = rsqrtf(var + EPS_);
        ar[b * C_ + c] = rstd * g;
        dr[b * C_ + c] = be - mu * rstd * g;
    }
}

// ---------------------------------------------------------------------------
// Kernel 3: convert the four 256x256 fp32 weight mats to bf16 (one pass)
// ---------------------------------------------------------------------------
__global__ __launch_bounds__(256) void w2bf(const float* __restrict__ W0,
                                            const float* __restrict__ W1,
                                            const float* __restrict__ W2,
                                            const float* __restrict__ W3,
                                            u16* __restrict__ dst) {
    int idx = blockIdx.x * 256 + threadIdx.x;   // 32768 threads, 8 elems each
    int m = idx >> 13, off = (idx & 8191) * 8;
    const float* s = (m == 0 ? W0 : m == 1 ? W1 : m == 2 ? W2 : W3) + off;
    float4 a = *(const float4*)s, b = *(const float4*)(s + 4);
    ushort4 lo; lo.x = f2bf(a.x); lo.y = f2bf(a.y); lo.z = f2bf(a.z); lo.w = f2bf(a.w);
    ushort4 hi; hi.x = f2bf(b.x); hi.y = f2bf(b.y); hi.z = f2bf(b.z); hi.w = f2bf(b.w);
    *(ushort4*)(dst + m * 65536 + off)     = lo;
    *(ushort4*)(dst + m * 65536 + off + 4) = hi;
}

// ---------------------------------------------------------------------------
// Kernel 4: normalize fp32 [b][c][P] -> bf16 transposed [b][P][256]
// (GN affine folded). LDS transpose, rows are phase-uniform -> no swizzle.
// ---------------------------------------------------------------------------
template<int P>
__global__ __launch_bounds__(256) void norm_tr(const float* __restrict__ X,
                                               const float* __restrict__ alpha,
                                               const float* __restrict__ delta,
                                               u16* __restrict__ Y) {
    __shared__ __align__(16) u16 S[64 * 256];   // [64 p][256 c] linear
    int b = blockIdx.z, p0 = blockIdx.x * 64;
    int tid = threadIdx.x;
    #pragma unroll
    for (int pass = 0; pass < 4; ++pass) {
        int qi = pass * 256 + tid;
        int cq = qi & 63, pq = qi >> 6;        // cq in low lane bits -> conflict-free writes
        float4 v[4];
        #pragma unroll
        for (int j = 0; j < 4; ++j) {
            int c = cq * 4 + j;
            v[j] = *(const float4*)(X + ((size_t)b * C_ + c) * P + p0 + pq * 4);
            float a = alpha[b * C_ + c], d = delta[b * C_ + c];
            v[j].x = v[j].x * a + d; v[j].y = v[j].y * a + d;
            v[j].z = v[j].z * a + d; v[j].w = v[j].w * a + d;
        }
        #pragma unroll
        for (int jj = 0; jj < 4; ++jj) {
            ushort4 o;
            o.x = f2bf(((const float*)&v[0])[jj]);
            o.y = f2bf(((const float*)&v[1])[jj]);
            o.z = f2bf(((const float*)&v[2])[jj]);
            o.w = f2bf(((const float*)&v[3])[jj]);
            *(ushort4*)&S[(pq * 4 + jj) * 256 + cq * 4] = o;
        }
    }
    __syncthreads();
    const char* Sb = (const char*)S;
    #pragma unroll
    for (int pass = 0; pass < 8; ++pass) {
        int i = pass * 256 + tid;
        int p = i >> 5, s = i & 31;
        uint4 d = *(const uint4*)(Sb + p * 512 + s * 16);
        *(uint4*)((char*)(Y + ((size_t)b * P + p0 + p) * C_) + s * 16) = d;
    }
}

// ---------------------------------------------------------------------------
// Kernel 5: 1x1 conv, all-bf16 MFMA. X [b][P][256] bf16, W [256][256] bf16.
// Tile 64 o x 64 p, K=256 single-stage via global_load_lds (pre-swz source).
// OUT=0: u16 [b][p][o] (q/k, *oscale) | OUT=1: u16 [b][o][p] (v)
// OUT=2: f32 [b][o][p] + resid       (final conv)
// ---------------------------------------------------------------------------
template<int OUT>
__global__ __launch_bounds__(256) void convA(const u16* __restrict__ Xb,
                                             const u16* __restrict__ Wb,
                                             const float* __restrict__ bias,
                                             const float* __restrict__ resid,
                                             void* __restrict__ Yv,
                                             int P, float oscale) {
    __shared__ __align__(16) char lds[65536];   // Xs 32K @0, Ws 32K @32768
    int b = blockIdx.z, p0 = blockIdx.x * 64, o0 = blockIdx.y * 64;
    int tid = threadIdx.x, w = tid >> 6, l = tid & 63, lg = l >> 4, ln = l & 15;
    int wm = w >> 1, wn = w & 1;
    const char* Xg = (const char*)(Xb + ((size_t)b * P + p0) * C_);   // contiguous 32 KB
    const char* Wg = (const char*)(Wb + (size_t)o0 * C_);             // contiguous 32 KB
    #pragma unroll
    for (int i = 0; i < 8; ++i) {
        int ci = i * 4 + w;
        int d = ci * 1024 + l * 16;
        int srco = (d & ~511) | ((d & 511) ^ (((d >> 9) & 7) << 4));
        gl16(Xg + srco, lds + ci * 1024);
        gl16(Wg + srco, lds + 32768 + ci * 1024);
    }
    asm volatile("s_waitcnt vmcnt(0)" ::: "memory");
    __syncthreads();

    f32x4 acc[2][2];
    #pragma unroll
    for (int mm = 0; mm < 2; ++mm)
        #pragma unroll
        for (int nn = 0; nn < 2; ++nn) acc[mm][nn] = (f32x4)0.f;

    #pragma unroll
    for (int f = 0; f < 8; ++f) {
        short8 xf[2], wf[2];
        #pragma unroll
        for (int nn = 0; nn < 2; ++nn) {
            int p = wn * 32 + nn * 16 + ln;
            xf[nn] = lds8(lds + p * 512 + ((f * 64 + lg * 16) ^ ((p & 7) << 4)));
        }
        #pragma unroll
        for (int mm = 0; mm < 2; ++mm) {
            int o = wm * 32 + mm * 16 + ln;
            wf[mm] = lds8(lds + 32768 + o * 512 + ((f * 64 + lg * 16) ^ ((o & 7) << 4)));
        }
        #pragma unroll
        for (int mm = 0; mm < 2; ++mm)
            #pragma unroll
            for (int nn = 0; nn < 2; ++nn) {
                if (OUT == 1) acc[mm][nn] = mfma16(xf[nn], wf[mm], acc[mm][nn]); // D[m=p][n=o]
                else          acc[mm][nn] = mfma16(wf[mm], xf[nn], acc[mm][nn]); // D[m=o][n=p]
            }
    }
    __syncthreads();   // before reusing lds[0..) as output staging

    if constexpr (OUT == 0) {
        // stage Os u16 [64 p][64 o] (128B rows, swz (p&7)<<4), pairs over o
        #pragma unroll
        for (int mm = 0; mm < 2; ++mm) {
            int obase = o0 + wm * 32 + mm * 16 + lg * 4;
            float b0 = bias[obase], b1 = bias[obase + 1], b2 = bias[obase + 2], b3 = bias[obase + 3];
            #pragma unroll
            for (int nn = 0; nn < 2; ++nn) {
                int pl = wn * 32 + nn * 16 + ln;
                int a = pl * 128 + ((wm * 64 + mm * 32 + lg * 8) ^ ((pl & 7) << 4));
                *(u32*)(lds + a)     = pk2bf((acc[mm][nn][0] + b0) * oscale, (acc[mm][nn][1] + b1) * oscale);
                *(u32*)(lds + a + 4) = pk2bf((acc[mm][nn][2] + b2) * oscale, (acc[mm][nn][3] + b3) * oscale);
            }
        }
        __syncthreads();
        u16* Y = (u16*)Yv;
        #pragma unroll
        for (int pass = 0; pass < 2; ++pass) {
            int i = pass * 256 + tid;
            int pl = i >> 3, s = i & 7;
            uint4 d = *(const uint4*)(lds + pl * 128 + ((s * 16) ^ ((pl & 7) << 4)));
            *(uint4*)(Y + (size_t)(b * P + p0 + pl) * C_ + o0 + s * 8) = d;
        }
    } else if constexpr (OUT == 1) {
        // stage Os u16 [64 o][64 p], pairs over p
        #pragma unroll
        for (int mm = 0; mm < 2; ++mm) {
            int ol = wm * 32 + mm * 16 + ln;
            float bo = bias[o0 + ol];
            #pragma unroll
            for (int nn = 0; nn < 2; ++nn) {
                int a = ol * 128 + ((wn * 64 + nn * 32 + lg * 8) ^ ((ol & 7) << 4));
                *(u32*)(lds + a)     = pk2bf(acc[mm][nn][0] + bo, acc[mm][nn][1] + bo);
                *(u32*)(lds + a + 4) = pk2bf(acc[mm][nn][2] + bo, acc[mm][nn][3] + bo);
            }
        }
        __syncthreads();
        u16* Y = (u16*)Yv;
        #pragma unroll
        for (int pass = 0; pass < 2; ++pass) {
            int i = pass * 256 + tid;
            int ol = i >> 3, s = i & 7;
            uint4 d = *(const uint4*)(lds + ol * 128 + ((s * 16) ^ ((ol & 7) << 4)));
            *(uint4*)(Y + (size_t)(b * C_ + o0 + ol) * P + p0 + s * 8) = d;
        }
    } else {
        // stage f32 [64 o][64 p] (256B rows, swz (o&7)<<4)
        #pragma unroll
        for (int mm = 0; mm < 2; ++mm) {
            int obase = wm * 32 + mm * 16 + lg * 4;
            #pragma unroll
            for (int r = 0; r < 4; ++r) {
                int ol = obase + r;
                float bo = bias[o0 + ol];
                #pragma unroll
                for (int nn = 0; nn < 2; ++nn) {
                    int a = ol * 256 + ((wn * 128 + nn * 64 + ln * 4) ^ ((ol & 7) << 4));
                    *(float*)(lds + a) = acc[mm][nn][r] + bo;
                }
            }
        }
        __syncthreads();
        float* Y = (float*)Yv;
        #pragma unroll
        for (int pass = 0; pass < 4; ++pass) {
            int i = pass * 256 + tid;
            int ol = i >> 4, s = i & 15;
            f32x4 dv = *(const f32x4*)(lds + ol * 256 + ((s * 16) ^ ((ol & 7) << 4)));
            size_t go = (size_t)(b * C_ + o0 + ol) * P + p0 + s * 4;
            float4 rv = *(const float4*)(resid + go);
            float4 o4;
            o4.x = dv[0] + rv.x; o4.y = dv[1] + rv.y; o4.z = dv[2] + rv.z; o4.w = dv[3] + rv.w;
            *(float4*)(Y + go) = o4;
        }
    }
}

// ---------------------------------------------------------------------------
// Kernel 6: MFMA flash cross-attention v2.
// Block = (b,t, 64 q), 4 waves x 16 q. KVBLK=32, K/V double-buffered via
// global_load_lds (pre-swz source), stage(kt+1) issued before compute(kt),
// one vmcnt(0)+barrier per kt. Swapped PV (mfma(vf,pf)) -> acc keyed by own
// q=ln (no shfl for rescale) and c-adjacent pairs -> [b][p][c] output.
// Defer-rescale THR=8 (T13).
// ---------------------------------------------------------------------------
__global__ __launch_bounds__(256) void attn2(const u16* __restrict__ qT,   // [b][8192][256]
                                             const u16* __restrict__ kT,   // [b][1024][256]
                                             const u16* __restrict__ vh,   // [b][256][1024]
                                             u16* __restrict__ ao) {       // [b][8192][256]
    __shared__ __align__(16) char lds[69632]; // K dbuf 2x16K @0, V dbuf 2x16K @32768, P 4x1K @65536
    int b = blockIdx.z, t = blockIdx.y, q0 = blockIdx.x * 64;
    int tid = threadIdx.x, w = tid >> 6, l = tid & 63, lg = l >> 4, ln = l & 15;

    const u16* Qrow = qT + ((size_t)b * PM_ + t * HW_ + q0 + w * 16 + ln) * C_;
    short8 qf[8];
    #pragma unroll
    for (int f = 0; f < 8; ++f)
        qf[f] = __builtin_bit_cast(short8, *(const uint4*)((const char*)Qrow + f * 64 + lg * 16));

    const char* Kb = (const char*)(kT + (size_t)b * PR_ * C_);
    const char* Vb = (const char*)(vh + (size_t)b * C_ * PR_);

    f32x4 acc[16];
    #pragma unroll
    for (int cc = 0; cc < 16; ++cc) acc[cc] = (f32x4)0.f;
    float m_r = -1e30f, l_r = 0.f;

    auto stage = [&](int buf, int kt) {
        const char* Kg = Kb + kt * 32 * 512;     // contiguous 16 KB [32k][256c]
        char* Kl = lds + buf * 16384;
        char* Vl = lds + 32768 + buf * 16384;
        #pragma unroll
        for (int i = 0; i < 4; ++i) {            // K: rows 512B, swz (k&7)<<4
            int ci = i * 4 + w;
            int d = ci * 1024 + l * 16;
            int srco = (d & ~511) | ((d & 511) ^ (((d >> 9) & 7) << 4));
            gl16(Kg + srco, Kl + ci * 1024);
        }
        #pragma unroll
        for (int i = 0; i < 4; ++i) {            // V: [256c][32k], rows 64B, swz ((c>>1)&3)<<4
            int ci = i * 4 + w;
            int d = ci * 1024 + l * 16;
            int c = d >> 6;
            int srco = c * 2048 + kt * 64 + ((d & 63) ^ (((c >> 1) & 3) << 4));
            gl16(Vb + srco, Vl + ci * 1024);
        }
    };

    stage(0, 0);
    asm volatile("s_waitcnt vmcnt(0)" ::: "memory");
    __syncthreads();

    char* Pl = lds + 65536 + w * 1024;           // per-wave P [16q][32k], rows 64B
    for (int kt = 0; kt < 32; ++kt) {
        int buf = kt & 1;
        if (kt < 31) stage(buf ^ 1, kt + 1);     // async prefetch overlaps compute
        const char* Kl = lds + buf * 16384;
        const char* Vl = lds + 32768 + buf * 16384;

        // ---- S^T = K · Q (rows k, cols q=ln) ----
        f32x4 s0 = (f32x4)0.f, s1 = (f32x4)0.f;
        #pragma unroll
        for (int f = 0; f < 8; ++f) {
            int r1 = 16 + ln;
            short8 k0f = lds8(Kl + ln * 512 + ((f * 64 + lg * 16) ^ ((ln & 7) << 4)));
            short8 k1f = lds8(Kl + r1 * 512 + ((f * 64 + lg * 16) ^ ((r1 & 7) << 4)));
            s0 = mfma16(k0f, qf[f], s0);
            s1 = mfma16(k1f, qf[f], s1);
        }

        // ---- online softmax, state keyed by q=ln; defer-rescale THR=8 ----
        float tm = fmaxf(fmaxf(fmaxf(s0[0], s0[1]), fmaxf(s0[2], s0[3])),
                         fmaxf(fmaxf(s1[0], s1[1]), fmaxf(s1[2], s1[3])));
        tm = fmaxf(tm, __shfl_xor(tm, 16));
        tm = fmaxf(tm, __shfl_xor(tm, 32));
        if (__any(tm > m_r + 8.f)) {
            float mn = fmaxf(m_r, tm);
            float sc = __expf(m_r - mn);
            m_r = mn; l_r *= sc;
            #pragma unroll
            for (int cc = 0; cc < 16; ++cc) {
                acc[cc][0] *= sc; acc[cc][1] *= sc; acc[cc][2] *= sc; acc[cc][3] *= sc;
            }
        }
        float p0v[4], p1v[4], rs = 0.f;
        #pragma unroll
        for (int r = 0; r < 4; ++r) { p0v[r] = __expf(s0[r] - m_r); rs += p0v[r]; }
        #pragma unroll
        for (int r = 0; r < 4; ++r) { p1v[r] = __expf(s1[r] - m_r); rs += p1v[r]; }
        rs += __shfl_xor(rs, 16);
        rs += __shfl_xor(rs, 32);
        l_r += rs;

        // ---- publish P rows q=ln (k = j*16 + 4lg + r) ----
        int sw = ((ln >> 1) & 3) << 4;
        int a0 = ln * 64 + ((lg * 8) ^ sw);
        *(u32*)(Pl + a0)     = pk2bf(p0v[0], p0v[1]);
        *(u32*)(Pl + a0 + 4) = pk2bf(p0v[2], p0v[3]);
        int a1 = ln * 64 + ((32 + lg * 8) ^ sw);
        *(u32*)(Pl + a1)     = pk2bf(p1v[0], p1v[1]);
        *(u32*)(Pl + a1 + 4) = pk2bf(p1v[2], p1v[3]);

        short8 pf = lds8(Pl + ln * 64 + ((lg * 16) ^ sw));

        // ---- O^T += V^T · P^T : D rows c, cols q=ln ----
        #pragma unroll
        for (int cc = 0; cc < 16; ++cc) {
            int c = cc * 16 + ln;
            short8 vf = lds8(Vl + c * 64 + ((lg * 16) ^ (((c >> 1) & 3) << 4)));
            acc[cc] = mfma16(vf, pf, acc[cc]);
        }

        asm volatile("s_waitcnt vmcnt(0)" ::: "memory");
        __syncthreads();
    }

    // ---- epilogue: normalize by own l_r, stage [64q][256c], coalesced out ----
    float invl = 1.f / l_r;
    char* Os = lds;                              // 32 KB, K-region reuse (post-barrier)
    int qrow = w * 16 + ln;
    #pragma unroll
    for (int cc = 0; cc < 16; ++cc) {
        int a = qrow * 512 + ((cc * 32 + lg * 8) ^ ((qrow & 7) << 4));
        *(u32*)(Os + a)     = pk2bf(acc[cc][0] * invl, acc[cc][1] * invl);
        *(u32*)(Os + a + 4) = pk2bf(acc[cc][2] * invl, acc[cc][3] * invl);
    }
    __syncthreads();
    u16* aob = ao + ((size_t)b * PM_ + t * HW_ + q0) * C_;
    #pragma unroll
    for (int pass = 0; pass < 8; ++pass) {
        int i = pass * 256 + tid;
        int qr = i >> 5, s = i & 31;
        uint4 d = *(const uint4*)(Os + qr * 512 + ((s * 16) ^ ((qr & 7) << 4)));
        *(uint4*)((char*)(aob + (size_t)qr * C_) + s * 16) = d;
    }
}

// ---------------------------------------------------------------------------
// Launcher. ws bytes:
//   0 part_m | 4096 part_r | 8192 am | 12288 dm | 16384 ar | 20480 dr
//   32768   Wbf 4x128KB (q,k,v,o)
//   1 MB    xnm bf16 [4][8192][256] (16 MB)  -- ALIASED with ao (attn output)
//   17 MB   xnr bf16 [4][1024][256] (2 MB)
//   19 MB   qT  (16 MB) | 35 MB kT (2 MB) | 37 MB vh (2 MB)   total ~39 MB
// ---------------------------------------------------------------------------
extern "C" void kernel_launch(void* const* d_in, const int* in_sizes, int n_in,
                              void* d_out, int out_size, void* d_ws, size_t ws_size,
                              hipStream_t stream) {
    const float* x_motion = (const float*)d_in[0];
    const float* x_ref    = (const float*)d_in[1];
    const float* gamma    = (const float*)d_in[2];
    const float* beta     = (const float*)d_in[3];
    const float* Wq = (const float*)d_in[4];
    const float* bq = (const float*)d_in[5];
    const float* Wk = (const float*)d_in[6];
    const float* bk = (const float*)d_in[7];
    const float* Wv = (const float*)d_in[8];
    const float* bv = (const float*)d_in[9];
    const float* Wo = (const float*)d_in[10];
    const float* bo = (const float*)d_in[11];
    float* out = (float*)d_out;
    char* base = (char*)d_ws;

    float* part_m = (float*)(base);
    float* part_r = (float*)(base + 4096);
    float* am = (float*)(base + 8192);
    float* dm = (float*)(base + 12288);
    float* ar = (float*)(base + 16384);
    float* dr = (float*)(base + 20480);
    u16* wall = (u16*)(base + 32768);
    u16* wqb = wall;
    u16* wkb = wall + 65536;
    u16* wvb = wall + 131072;
    u16* wob = wall + 196608;
    u16* xnm = (u16*)(base + 1048576);                             // 16 MB
    u16* aoh = xnm;                                                // alias (xnm dead after conv-q)
    u16* xnr = (u16*)(base + 1048576 + 16777216);                  // 2 MB
    u16* qT  = (u16*)(base + 1048576 + 16777216 + 2097152);        // 16 MB
    u16* kTp = (u16*)(base + 1048576 + 2 * 16777216 + 2097152);    // 2 MB
    u16* vh  = (u16*)(base + 1048576 + 2 * 16777216 + 2 * 2097152);// 2 MB

    gn_stats<<<dim3(B_ * NBM), 256, 0, stream>>>(x_motion, NM_, NBM, part_m);
    gn_stats<<<dim3(B_ * NBR), 256, 0, stream>>>(x_ref, NR_, NBR, part_r);
    gn_finalize<<<dim3(1), 256, 0, stream>>>(part_m, part_r, gamma, beta, am, dm, ar, dr);
    w2bf<<<dim3(128), 256, 0, stream>>>(Wq, Wk, Wv, Wo, wall);

    norm_tr<PM_><<<dim3(PM_ / 64, 1, B_), 256, 0, stream>>>(x_motion, am, dm, xnm);
    norm_tr<PR_><<<dim3(PR_ / 64, 1, B_), 256, 0, stream>>>(x_ref, ar, dr, xnr);

    // q: [b][p][c] bf16, pre-scaled c^-0.5 = 1/16
    convA<0><<<dim3(PM_ / 64, 4, B_), 256, 0, stream>>>(xnm, wqb, bq, nullptr, qT, PM_, 0.0625f);
    // k: [b][k][c]
    convA<0><<<dim3(PR_ / 64, 4, B_), 256, 0, stream>>>(xnr, wkb, bk, nullptr, kTp, PR_, 1.f);
    // v: [b][c][k]
    convA<1><<<dim3(PR_ / 64, 4, B_), 256, 0, stream>>>(xnr, wvb, bv, nullptr, vh, PR_, 1.f);

    attn2<<<dim3(16, T_, B_), 256, 0, stream>>>(qT, kTp, vh, aoh);

    // final: bf16 [b][p][c] in, fp32 [b][c][p] out + residual
    convA<2><<<dim3(PM_ / 64, 4, B_), 256, 0, stream>>>(aoh, wob, bo, x_motion, out, PM_, 1.f);
}

// Round 7
// 127.868 us; speedup vs baseline: 9.1240x; 1.1268x over previous
//
#include <hip/hip_runtime.h>
#include <math.h>
#include <stdint.h>

#define B_   4
#define C_   256
#define T_   8
#define HW_  1024
#define PM_  8192
#define PR_  1024
#define NM_  (C_ * PM_)
#define NR_  (C_ * PR_)
#define NBM  128
#define NBR  16
#define EPS_ 1e-6f
// c^-0.5 * log2(e): fold softmax base-2 conversion into Q so attn uses exp2
#define QSCALE 0.09016844f

typedef unsigned short u16;
typedef unsigned int u32;
typedef __attribute__((ext_vector_type(8))) short short8;   // 8 bf16 = 4 VGPR
typedef __attribute__((ext_vector_type(4))) float f32x4;
typedef __attribute__((ext_vector_type(16))) float f32x16;

__device__ inline u16 f2bf(float f) {                 // RNE f32->bf16
    uint32_t u = __builtin_bit_cast(uint32_t, f);
    u += 0x7fffu + ((u >> 16) & 1u);
    return (u16)(u >> 16);
}
__device__ inline u32 pk2bf(float a, float b) {
    return (u32)f2bf(a) | ((u32)f2bf(b) << 16);
}

__device__ inline f32x4 mfma16(short8 a, short8 b, f32x4 c) {
    f32x4 d;
    asm("v_mfma_f32_16x16x32_bf16 %0, %1, %2, %3" : "=v"(d) : "v"(a), "v"(b), "0"(c));
    return d;
}
__device__ inline f32x16 mfma32(short8 a, short8 b, f32x16 c) {
    f32x16 d;
    asm("v_mfma_f32_32x32x16_bf16 %0, %1, %2, %3" : "=v"(d) : "v"(a), "v"(b), "0"(c));
    return d;
}
__device__ __forceinline__ short8 lds8(const char* p) {
    return __builtin_bit_cast(short8, *(const uint4*)p);
}
// async global->LDS, 16B/lane; dest = wave-uniform base + lane*16 (linear).
__device__ __forceinline__ void gl16(const void* g, void* l) {
    __builtin_amdgcn_global_load_lds(
        reinterpret_cast<const uint32_t __attribute__((address_space(1)))*>(
            reinterpret_cast<uintptr_t>(g)),
        reinterpret_cast<uint32_t __attribute__((address_space(3)))*>(
            reinterpret_cast<uintptr_t>(l)),
        16, 0, 0);
}

// ---------------------------------------------------------------------------
// Kernel 1 (merged): GroupNorm partial sums for motion (blocks 0..511) and
// ref (blocks 512..575), deterministic two-stage.
// ---------------------------------------------------------------------------
__device__ void gn_body(const float* __restrict__ x, int per_sample, int nblk,
                        float* __restrict__ part, int bid) {
    int b   = bid / nblk;
    int blk = bid % nblk;
    const float* xb = x + (size_t)b * per_sample;
    int chunk = per_sample / nblk;
    int base  = blk * chunk;
    float s = 0.f, s2 = 0.f;
    for (int i = threadIdx.x * 4; i < chunk; i += 256 * 4) {
        float4 v = *(const float4*)(xb + base + i);
        s  += v.x + v.y + v.z + v.w;
        s2 += v.x * v.x + v.y * v.y + v.z * v.z + v.w * v.w;
    }
    #pragma unroll
    for (int off = 32; off; off >>= 1) {
        s  += __shfl_down(s, off);
        s2 += __shfl_down(s2, off);
    }
    __shared__ float red[8];
    int wid = threadIdx.x >> 6, lane = threadIdx.x & 63;
    if (lane == 0) { red[wid * 2] = s; red[wid * 2 + 1] = s2; }
    __syncthreads();
    if (threadIdx.x == 0) {
        for (int w = 1; w < 4; ++w) { s += red[w * 2]; s2 += red[w * 2 + 1]; }
        part[(size_t)(b * nblk + blk) * 2]     = s;
        part[(size_t)(b * nblk + blk) * 2 + 1] = s2;
    }
}
__global__ __launch_bounds__(256) void gn_all(const float* __restrict__ xm,
                                              const float* __restrict__ xr,
                                              float* __restrict__ part_m,
                                              float* __restrict__ part_r) {
    if (blockIdx.x < 512) gn_body(xm, NM_, NBM, part_m, blockIdx.x);
    else                  gn_body(xr, NR_, NBR, part_r, blockIdx.x - 512);
}

// ---------------------------------------------------------------------------
// Kernel 2 (merged): block 128 = GN finalize -> per (b,c) affine;
// blocks 0..127 = fp32->bf16 conversion of the four weight matrices.
// ---------------------------------------------------------------------------
__global__ __launch_bounds__(256) void fin_w2bf(const float* __restrict__ part_m,
                                                const float* __restrict__ part_r,
                                                const float* __restrict__ gamma,
                                                const float* __restrict__ beta,
                                                float* __restrict__ am, float* __restrict__ dm,
                                                float* __restrict__ ar, float* __restrict__ dr,
                                                const float* __restrict__ W0,
                                                const float* __restrict__ W1,
                                                const float* __restrict__ W2,
                                                const float* __restrict__ W3,
                                                u16* __restrict__ dst) {
    if (blockIdx.x == 128) {
        int c = threadIdx.x;
        float g = gamma[c], be = beta[c];
        for (int b = 0; b < B_; ++b) {
            float s = 0.f, s2 = 0.f;
            for (int i = 0; i < NBM; ++i) { s += part_m[(b * NBM + i) * 2]; s2 += part_m[(b * NBM + i) * 2 + 1]; }
            float mu   = s / (float)NM_;
            float var  = s2 / (float)NM_ - mu * mu;
            float rstd = rsqrtf(var + EPS_);
            am[b * C_ + c] = rstd * g;
            dm[b * C_ + c] = be - mu * rstd * g;

            s = 0.f; s2 = 0.f;
            for (int i = 0; i < NBR; ++i) { s += part_r[(b * NBR + i) * 2]; s2 += part_r[(b * NBR + i) * 2 + 1]; }
            mu   = s / (float)NR_;
            var  = s2 / (float)NR_ - mu * mu;
            rstd = rsqrtf(var + EPS_);
            ar[b * C_ + c] = rstd * g;
            dr[b * C_ + c] = be - mu * rstd * g;
        }
        return;
    }
    int idx = blockIdx.x * 256 + threadIdx.x;   // 32768 threads, 8 elems each
    int m = idx >> 13, off = (idx & 8191) * 8;
    const float* s = (m == 0 ? W0 : m == 1 ? W1 : m == 2 ? W2 : W3) + off;
    float4 a = *(const float4*)s, b = *(const float4*)(s + 4);
    ushort4 lo; lo.x = f2bf(a.x); lo.y = f2bf(a.y); lo.z = f2bf(a.z); lo.w = f2bf(a.w);
    ushort4 hi; hi.x = f2bf(b.x); hi.y = f2bf(b.y); hi.z = f2bf(b.z); hi.w = f2bf(b.w);
    *(ushort4*)(dst + m * 65536 + off)     = lo;
    *(ushort4*)(dst + m * 65536 + off + 4) = hi;
}

// ---------------------------------------------------------------------------
// Kernel 3 (merged): normalize fp32 [b][c][P] -> bf16 transposed [b][P][256]
// for motion (blocks 0..511) and ref (512..575). LDS transpose.
// ---------------------------------------------------------------------------
__device__ void norm_body(const float* __restrict__ X,
                          const float* __restrict__ alpha,
                          const float* __restrict__ delta,
                          u16* __restrict__ Y, int P, int px, int b,
                          u16* S) {
    int p0 = px * 64;
    int tid = threadIdx.x;
    #pragma unroll
    for (int pass = 0; pass < 4; ++pass) {
        int qi = pass * 256 + tid;
        int cq = qi & 63, pq = qi >> 6;
        float4 v[4];
        #pragma unroll
        for (int j = 0; j < 4; ++j) {
            int c = cq * 4 + j;
            v[j] = *(const float4*)(X + ((size_t)b * C_ + c) * P + p0 + pq * 4);
            float a = alpha[b * C_ + c], d = delta[b * C_ + c];
            v[j].x = v[j].x * a + d; v[j].y = v[j].y * a + d;
            v[j].z = v[j].z * a + d; v[j].w = v[j].w * a + d;
        }
        #pragma unroll
        for (int jj = 0; jj < 4; ++jj) {
            ushort4 o;
            o.x = f2bf(((const float*)&v[0])[jj]);
            o.y = f2bf(((const float*)&v[1])[jj]);
            o.z = f2bf(((const float*)&v[2])[jj]);
            o.w = f2bf(((const float*)&v[3])[jj]);
            *(ushort4*)&S[(pq * 4 + jj) * 256 + cq * 4] = o;
        }
    }
    __syncthreads();
    const char* Sb = (const char*)S;
    #pragma unroll
    for (int pass = 0; pass < 8; ++pass) {
        int i = pass * 256 + tid;
        int p = i >> 5, s = i & 31;
        uint4 d = *(const uint4*)(Sb + p * 512 + s * 16);
        *(uint4*)((char*)(Y + ((size_t)b * P + p0 + p) * C_) + s * 16) = d;
    }
}
__global__ __launch_bounds__(256) void norm_all(const float* __restrict__ xm,
                                                const float* __restrict__ xr,
                                                const float* __restrict__ am,
                                                const float* __restrict__ dm,
                                                const float* __restrict__ ar,
                                                const float* __restrict__ dr,
                                                u16* __restrict__ xnm,
                                                u16* __restrict__ xnr) {
    __shared__ __align__(16) u16 S[64 * 256];
    int bid = blockIdx.x;
    if (bid < 512) norm_body(xm, am, dm, xnm, PM_, bid & 127, bid >> 7, S);
    else { int i = bid - 512; norm_body(xr, ar, dr, xnr, PR_, i & 15, i >> 4, S); }
}

// ---------------------------------------------------------------------------
// 1x1 conv body, all-bf16 MFMA (16x16x32). X [b][P][256], W [256o][256c].
// Tile 64 o x 64 p, K=256 single-stage via global_load_lds (pre-swz source).
// OUT=0: u16 [b][p][o] (*oscale) | OUT=1: u16 [b][o][p] | OUT=2: f32 [b][o][p]+resid
// ---------------------------------------------------------------------------
template<int OUT>
__device__ void convA_body(char* lds,
                           const u16* __restrict__ Xb, const u16* __restrict__ Wb,
                           const float* __restrict__ bias, const float* __restrict__ resid,
                           void* __restrict__ Yv, int P, float oscale,
                           int px, int oy, int b) {
    int p0 = px * 64, o0 = oy * 64;
    int tid = threadIdx.x;
    int w = tid >> 6, l = tid & 63, lg = l >> 4, ln = l & 15;
    int wm = w >> 1, wn = w & 1;
    const char* Xg = (const char*)(Xb + ((size_t)b * P + p0) * C_);   // contiguous 32 KB
    const char* Wg = (const char*)(Wb + (size_t)o0 * C_);             // contiguous 32 KB
    #pragma unroll
    for (int i = 0; i < 8; ++i) {
        int ci = i * 4 + w;
        int d = ci * 1024 + l * 16;
        int srco = (d & ~511) | ((d & 511) ^ (((d >> 9) & 7) << 4));
        gl16(Xg + srco, lds + ci * 1024);
        gl16(Wg + srco, lds + 32768 + ci * 1024);
    }
    asm volatile("s_waitcnt vmcnt(0)" ::: "memory");
    __syncthreads();

    f32x4 acc[2][2];
    #pragma unroll
    for (int mm = 0; mm < 2; ++mm)
        #pragma unroll
        for (int nn = 0; nn < 2; ++nn) acc[mm][nn] = (f32x4)0.f;

    #pragma unroll
    for (int f = 0; f < 8; ++f) {
        short8 xf[2], wf[2];
        #pragma unroll
        for (int nn = 0; nn < 2; ++nn) {
            int p = wn * 32 + nn * 16 + ln;
            xf[nn] = lds8(lds + p * 512 + ((f * 64 + lg * 16) ^ ((p & 7) << 4)));
        }
        #pragma unroll
        for (int mm = 0; mm < 2; ++mm) {
            int o = wm * 32 + mm * 16 + ln;
            wf[mm] = lds8(lds + 32768 + o * 512 + ((f * 64 + lg * 16) ^ ((o & 7) << 4)));
        }
        #pragma unroll
        for (int mm = 0; mm < 2; ++mm)
            #pragma unroll
            for (int nn = 0; nn < 2; ++nn) {
                if (OUT == 1) acc[mm][nn] = mfma16(xf[nn], wf[mm], acc[mm][nn]); // D[m=p][n=o]
                else          acc[mm][nn] = mfma16(wf[mm], xf[nn], acc[mm][nn]); // D[m=o][n=p]
            }
    }
    __syncthreads();

    if constexpr (OUT == 0) {
        #pragma unroll
        for (int mm = 0; mm < 2; ++mm) {
            int obase = o0 + wm * 32 + mm * 16 + lg * 4;
            float b0 = bias[obase], b1 = bias[obase + 1], b2 = bias[obase + 2], b3 = bias[obase + 3];
            #pragma unroll
            for (int nn = 0; nn < 2; ++nn) {
                int pl = wn * 32 + nn * 16 + ln;
                int a = pl * 128 + ((wm * 64 + mm * 32 + lg * 8) ^ ((pl & 7) << 4));
                *(u32*)(lds + a)     = pk2bf((acc[mm][nn][0] + b0) * oscale, (acc[mm][nn][1] + b1) * oscale);
                *(u32*)(lds + a + 4) = pk2bf((acc[mm][nn][2] + b2) * oscale, (acc[mm][nn][3] + b3) * oscale);
            }
        }
        __syncthreads();
        u16* Y = (u16*)Yv;
        #pragma unroll
        for (int pass = 0; pass < 2; ++pass) {
            int i = pass * 256 + tid;
            int pl = i >> 3, s = i & 7;
            uint4 d = *(const uint4*)(lds + pl * 128 + ((s * 16) ^ ((pl & 7) << 4)));
            *(uint4*)(Y + (size_t)(b * P + p0 + pl) * C_ + o0 + s * 8) = d;
        }
    } else if constexpr (OUT == 1) {
        #pragma unroll
        for (int mm = 0; mm < 2; ++mm) {
            int ol = wm * 32 + mm * 16 + ln;
            float bo = bias[o0 + ol];
            #pragma unroll
            for (int nn = 0; nn < 2; ++nn) {
                int a = ol * 128 + ((wn * 64 + nn * 32 + lg * 8) ^ ((ol & 7) << 4));
                *(u32*)(lds + a)     = pk2bf(acc[mm][nn][0] + bo, acc[mm][nn][1] + bo);
                *(u32*)(lds + a + 4) = pk2bf(acc[mm][nn][2] + bo, acc[mm][nn][3] + bo);
            }
        }
        __syncthreads();
        u16* Y = (u16*)Yv;
        #pragma unroll
        for (int pass = 0; pass < 2; ++pass) {
            int i = pass * 256 + tid;
            int ol = i >> 3, s = i & 7;
            uint4 d = *(const uint4*)(lds + ol * 128 + ((s * 16) ^ ((ol & 7) << 4)));
            *(uint4*)(Y + (size_t)(b * C_ + o0 + ol) * P + p0 + s * 8) = d;
        }
    } else {
        #pragma unroll
        for (int mm = 0; mm < 2; ++mm) {
            int obase = wm * 32 + mm * 16 + lg * 4;
            #pragma unroll
            for (int r = 0; r < 4; ++r) {
                int ol = obase + r;
                float bo = bias[o0 + ol];
                #pragma unroll
                for (int nn = 0; nn < 2; ++nn) {
                    int a = ol * 256 + ((wn * 128 + nn * 64 + ln * 4) ^ ((ol & 7) << 4));
                    *(float*)(lds + a) = acc[mm][nn][r] + bo;
                }
            }
        }
        __syncthreads();
        float* Y = (float*)Yv;
        #pragma unroll
        for (int pass = 0; pass < 4; ++pass) {
            int i = pass * 256 + tid;
            int ol = i >> 4, s = i & 15;
            f32x4 dv = *(const f32x4*)(lds + ol * 256 + ((s * 16) ^ ((ol & 7) << 4)));
            size_t go = (size_t)(b * C_ + o0 + ol) * P + p0 + s * 4;
            float4 rv = *(const float4*)(resid + go);
            float4 o4;
            o4.x = dv[0] + rv.x; o4.y = dv[1] + rv.y; o4.z = dv[2] + rv.z; o4.w = dv[3] + rv.w;
            *(float4*)(Y + go) = o4;
        }
    }
}

// Kernel 4 (merged): q (blocks 0..2047), k (2048..2303), v (2304..2559)
__global__ __launch_bounds__(256) void convQKV(const u16* __restrict__ xnm,
                                               const u16* __restrict__ xnr,
                                               const u16* __restrict__ wall,
                                               const float* __restrict__ bq,
                                               const float* __restrict__ bk,
                                               const float* __restrict__ bv,
                                               u16* __restrict__ qT,
                                               u16* __restrict__ kT,
                                               u16* __restrict__ vh) {
    __shared__ __align__(16) char lds[65536];
    int bid = blockIdx.x;
    if (bid < 2048) {
        convA_body<0>(lds, xnm, wall, bq, nullptr, qT, PM_, QSCALE,
                      bid & 127, (bid >> 7) & 3, bid >> 9);
    } else if (bid < 2304) {
        int i = bid - 2048;
        convA_body<0>(lds, xnr, wall + 65536, bk, nullptr, kT, PR_, 1.f,
                      i & 15, (i >> 4) & 3, i >> 6);
    } else {
        int i = bid - 2304;
        convA_body<1>(lds, xnr, wall + 131072, bv, nullptr, vh, PR_, 1.f,
                      i & 15, (i >> 4) & 3, i >> 6);
    }
}

// Kernel 6: final conv, bf16 [b][p][c] in -> fp32 [b][c][p] + residual
__global__ __launch_bounds__(256) void convO(const u16* __restrict__ aoh,
                                             const u16* __restrict__ wall,
                                             const float* __restrict__ bo,
                                             const float* __restrict__ resid,
                                             float* __restrict__ out) {
    __shared__ __align__(16) char lds[65536];
    convA_body<2>(lds, aoh, wall + 196608, bo, resid, out, PM_, 1.f,
                  blockIdx.x, blockIdx.y, blockIdx.z);
}

// ---------------------------------------------------------------------------
// Kernel 5: flash cross-attention, 32x32x16 MFMA.
// Block = (b,t, 128 q), 4 waves x 32 q each. KVBLK=64, grid 256 (1 block/CU).
// K [64k][256c] + V [256c][64k] double-buffered via global_load_lds with
// pre-swizzled source. S^T = mfma32(K,Q) -> lane owns q=l&31, keys split by hi.
// P redistribution via per-wave LDS round-trip [32q][64k] (128B rows,
// XOR-swz (q&7)<<4). Online softmax: m init -1e30, defer-max THR=8, exp2.
// ---------------------------------------------------------------------------
__global__ __launch_bounds__(256, 1) void attn4(const u16* __restrict__ qT,  // [b][8192][256]
                                                const u16* __restrict__ kT,  // [b][1024][256]
                                                const u16* __restrict__ vh,  // [b][256][1024]
                                                u16* __restrict__ ao) {      // [b][8192][256]
    __shared__ __align__(16) char lds[147456]; // K dbuf 2x32K @0, V dbuf 2x32K @65536, P 4x4K @131072
    int b = blockIdx.z, t = blockIdx.y, q0 = blockIdx.x * 128;
    int tid = threadIdx.x, w = tid >> 6, l = tid & 63;
    int m31 = l & 31, hi = l >> 5;

    // Q fragments (B operand), resident: lane holds Q[q=m31][c = ch*16 + 8*hi + e]
    const char* Qrow = (const char*)(qT + ((size_t)b * PM_ + t * HW_ + q0 + w * 32 + m31) * C_);
    short8 qf[16];
    #pragma unroll
    for (int ch = 0; ch < 16; ++ch)
        qf[ch] = __builtin_bit_cast(short8, *(const uint4*)(Qrow + ch * 32 + hi * 16));

    const char* Kb = (const char*)(kT + (size_t)b * PR_ * C_);
    const char* Vb = (const char*)(vh + (size_t)b * C_ * PR_);

    f32x16 acc[8];
    #pragma unroll
    for (int cb = 0; cb < 8; ++cb) acc[cb] = (f32x16)0.f;
    float m_r = -1e30f, l_r = 0.f;

    auto stage = [&](int buf, int kt) {
        char* Kl = lds + buf * 32768;
        char* Vl = lds + 65536 + buf * 32768;
        #pragma unroll
        for (int i = 0; i < 8; ++i) {            // K tile: contiguous 32KB, rows 512B
            int ci = i * 4 + w;
            int d = ci * 1024 + l * 16;
            int srco = (d & ~511) | ((d & 511) ^ (((d >> 9) & 7) << 4));
            gl16(Kb + (size_t)kt * 32768 + srco, Kl + ci * 1024);
        }
        #pragma unroll
        for (int i = 0; i < 8; ++i) {            // V tile: [256c][64k], rows 128B
            int ci = i * 4 + w;
            int d = ci * 1024 + l * 16;
            int c = d >> 7, s = (d >> 4) & 7;
            int srco = c * 2048 + kt * 128 + ((s * 16) ^ ((c & 7) << 4));
            gl16(Vb + srco, Vl + ci * 1024);
        }
    };

    stage(0, 0);
    asm volatile("s_waitcnt vmcnt(0)" ::: "memory");
    __syncthreads();

    char* Pw = lds + 131072 + w * 4096;          // per-wave P [32q][128B], swz (q&7)<<4
    int swzp = (m31 & 7) << 4;

    for (int kt = 0; kt < 16; ++kt) {
        int buf = kt & 1;
        if (kt < 15) stage(buf ^ 1, kt + 1);     // async prefetch overlaps compute
        const char* Kl = lds + buf * 32768;
        const char* Vl = lds + 65536 + buf * 32768;

        // ---- S^T = K · Q : rows k (0..63), cols q = m31 ----
        f32x16 s0 = (f32x16)0.f, s1 = (f32x16)0.f;
        #pragma unroll
        for (int ch = 0; ch < 16; ++ch) {
            int off = (ch * 32 + hi * 16) ^ swzp;
            short8 k0f = lds8(Kl + m31 * 512 + off);
            short8 k1f = lds8(Kl + (32 + m31) * 512 + off);
            s0 = mfma32(k0f, qf[ch], s0);
            s1 = mfma32(k1f, qf[ch], s1);
        }

        // ---- online softmax (defer-max THR=8; exp2) ----
        float tm = -1e30f;
        #pragma unroll
        for (int e = 0; e < 16; ++e) tm = fmaxf(tm, fmaxf(s0[e], s1[e]));
        if (__any(tm > m_r + 8.f)) {             // fires on tile 0, then rarely
            float tmax = fmaxf(tm, __shfl_xor(tm, 32));
            float mn = fmaxf(m_r, tmax);
            float sc = __builtin_amdgcn_exp2f(m_r - mn);
            l_r *= sc;
            #pragma unroll
            for (int cb = 0; cb < 8; ++cb)
                #pragma unroll
                for (int e = 0; e < 16; ++e) acc[cb][e] *= sc;
            m_r = mn;
        }
        float p0[16], p1[16], rs = 0.f;
        #pragma unroll
        for (int e = 0; e < 16; ++e) { p0[e] = __builtin_amdgcn_exp2f(s0[e] - m_r); rs += p0[e]; }
        #pragma unroll
        for (int e = 0; e < 16; ++e) { p1[e] = __builtin_amdgcn_exp2f(s1[e] - m_r); rs += p1[e]; }
        l_r += rs;                                // per-lane partial; reduced once at end

        // ---- publish P: row q=m31, key0 = 8a + 4hi, e-block = 4*(a&3) ----
        #pragma unroll
        for (int a = 0; a < 8; ++a) {
            const float* parr = (a < 4) ? p0 : p1;
            int eb = (a & 3) * 4;
            uint2 d;
            d.x = pk2bf(parr[eb + 0], parr[eb + 1]);
            d.y = pk2bf(parr[eb + 2], parr[eb + 3]);
            *(uint2*)(Pw + m31 * 128 + ((a * 16 + hi * 8) ^ swzp)) = d;
        }

        // ---- PV B-fragments: one b128 per 16-key chunk from own q-row ----
        short8 bP[4];
        #pragma unroll
        for (int kc = 0; kc < 4; ++kc)
            bP[kc] = lds8(Pw + m31 * 128 + ((kc * 32 + hi * 16) ^ swzp));

        // ---- O^T += V^T · P : rows c, cols q = m31 ----
        #pragma unroll
        for (int cb = 0; cb < 8; ++cb) {
            int c = cb * 32 + m31;
            int rowb = c * 128, swzc = (c & 7) << 4;
            #pragma unroll
            for (int kc = 0; kc < 4; ++kc) {
                short8 vf = lds8(Vl + rowb + ((kc * 32 + hi * 16) ^ swzc));
                acc[cb] = mfma32(vf, bP[kc], acc[cb]);
            }
        }

        asm volatile("s_waitcnt vmcnt(0)" ::: "memory");
        __syncthreads();
    }

    // ---- epilogue: reduce l across k-halves, normalize, stage [128q][256c] ----
    l_r += __shfl_xor(l_r, 32);
    float invl = 1.f / l_r;
    char* Os = lds;                               // 64 KB staging (post-barrier reuse)
    int q = w * 32 + m31;
    int swzq = (q & 7) << 4;
    #pragma unroll
    for (int cb = 0; cb < 8; ++cb)
        #pragma unroll
        for (int m = 0; m < 4; ++m) {
            uint2 d;
            d.x = pk2bf(acc[cb][4 * m + 0] * invl, acc[cb][4 * m + 1] * invl);
            d.y = pk2bf(acc[cb][4 * m + 2] * invl, acc[cb][4 * m + 3] * invl);
            *(uint2*)(Os + q * 512 + ((cb * 64 + m * 16 + hi * 8) ^ swzq)) = d;
        }
    __syncthreads();
    u16* aob = ao + ((size_t)b * PM_ + t * HW_ + q0) * C_;
    // 128 q rows x 512 B = 64 KB -> 16 passes (R6 bug: was 8, dropped rows 64..127)
    #pragma unroll
    for (int pass = 0; pass < 16; ++pass) {
        int i = pass * 256 + tid;
        int qr = i >> 5, s = i & 31;
        uint4 d = *(const uint4*)(Os + qr * 512 + ((s * 16) ^ ((qr & 7) << 4)));
        *(uint4*)((char*)(aob + (size_t)qr * C_) + s * 16) = d;
    }
}

// ---------------------------------------------------------------------------
// Launcher. ws bytes:
//   0 part_m | 4096 part_r | 8192 am | 12288 dm | 16384 ar | 20480 dr
//   32768   Wbf 4x128KB (q,k,v,o)
//   1 MB    xnm bf16 [4][8192][256] (16 MB)  -- ALIASED with ao
//   17 MB   xnr (2 MB) | 19 MB qT (16 MB) | 35 MB kT (2 MB) | 37 MB vh (2 MB)
// ---------------------------------------------------------------------------
extern "C" void kernel_launch(void* const* d_in, const int* in_sizes, int n_in,
                              void* d_out, int out_size, void* d_ws, size_t ws_size,
                              hipStream_t stream) {
    const float* x_motion = (const float*)d_in[0];
    const float* x_ref    = (const float*)d_in[1];
    const float* gamma    = (const float*)d_in[2];
    const float* beta     = (const float*)d_in[3];
    const float* Wq = (const float*)d_in[4];
    const float* bq = (const float*)d_in[5];
    const float* Wk = (const float*)d_in[6];
    const float* bk = (const float*)d_in[7];
    const float* Wv = (const float*)d_in[8];
    const float* bv = (const float*)d_in[9];
    const float* Wo = (const float*)d_in[10];
    const float* bo = (const float*)d_in[11];
    float* out = (float*)d_out;
    char* base = (char*)d_ws;

    float* part_m = (float*)(base);
    float* part_r = (float*)(base + 4096);
    float* am = (float*)(base + 8192);
    float* dm = (float*)(base + 12288);
    float* ar = (float*)(base + 16384);
    float* dr = (float*)(base + 20480);
    u16* wall = (u16*)(base + 32768);
    u16* xnm = (u16*)(base + 1048576);                             // 16 MB
    u16* aoh = xnm;                                                // alias (xnm dead after convQKV)
    u16* xnr = (u16*)(base + 1048576 + 16777216);                  // 2 MB
    u16* qT  = (u16*)(base + 1048576 + 16777216 + 2097152);        // 16 MB
    u16* kTp = (u16*)(base + 1048576 + 2 * 16777216 + 2097152);    // 2 MB
    u16* vh  = (u16*)(base + 1048576 + 2 * 16777216 + 2 * 2097152);// 2 MB

    gn_all<<<dim3(576), 256, 0, stream>>>(x_motion, x_ref, part_m, part_r);
    fin_w2bf<<<dim3(129), 256, 0, stream>>>(part_m, part_r, gamma, beta,
                                            am, dm, ar, dr, Wq, Wk, Wv, Wo, wall);
    norm_all<<<dim3(576), 256, 0, stream>>>(x_motion, x_ref, am, dm, ar, dr, xnm, xnr);
    convQKV<<<dim3(2560), 256, 0, stream>>>(xnm, xnr, wall, bq, bk, bv, qT, kTp, vh);
    attn4<<<dim3(8, T_, B_), 256, 0, stream>>>(qT, kTp, vh, aoh);
    convO<<<dim3(PM_ / 64, 4, B_), 256, 0, stream>>>(aoh, wall, bo, x_motion, out);
}

// Round 10
// 127.646 us; speedup vs baseline: 9.1400x; 1.0017x over previous
//
#include <hip/hip_runtime.h>
#include <math.h>
#include <stdint.h>

#define B_   4
#define C_   256
#define T_   8
#define HW_  1024
#define PM_  8192
#define PR_  1024
#define NM_  (C_ * PM_)
#define NR_  (C_ * PR_)
#define NBM  128
#define NBR  16
#define EPS_ 1e-6f
// c^-0.5 * log2(e): fold softmax base-2 conversion into Q so attn uses exp2
#define QSCALE 0.09016844f

typedef unsigned short u16;
typedef unsigned int u32;
typedef __attribute__((ext_vector_type(8))) short short8;   // 8 bf16 = 4 VGPR
typedef __attribute__((ext_vector_type(4))) float f32x4;
typedef __attribute__((ext_vector_type(16))) float f32x16;

__device__ inline u16 f2bf(float f) {                 // RNE f32->bf16
    uint32_t u = __builtin_bit_cast(uint32_t, f);
    u += 0x7fffu + ((u >> 16) & 1u);
    return (u16)(u >> 16);
}
__device__ inline u32 pk2bf(float a, float b) {
    return (u32)f2bf(a) | ((u32)f2bf(b) << 16);
}

__device__ inline f32x4 mfma16(short8 a, short8 b, f32x4 c) {
    f32x4 d;
    asm("v_mfma_f32_16x16x32_bf16 %0, %1, %2, %3" : "=v"(d) : "v"(a), "v"(b), "0"(c));
    return d;
}
__device__ inline f32x16 mfma32(short8 a, short8 b, f32x16 c) {
    f32x16 d;
    asm("v_mfma_f32_32x32x16_bf16 %0, %1, %2, %3" : "=v"(d) : "v"(a), "v"(b), "0"(c));
    return d;
}
__device__ __forceinline__ short8 lds8(const char* p) {
    return __builtin_bit_cast(short8, *(const uint4*)p);
}
// async global->LDS, 16B/lane; dest = wave-uniform base + lane*16 (linear).
__device__ __forceinline__ void gl16(const void* g, void* l) {
    __builtin_amdgcn_global_load_lds(
        reinterpret_cast<const uint32_t __attribute__((address_space(1)))*>(
            reinterpret_cast<uintptr_t>(g)),
        reinterpret_cast<uint32_t __attribute__((address_space(3)))*>(
            reinterpret_cast<uintptr_t>(l)),
        16, 0, 0);
}

// ---------------------------------------------------------------------------
// Kernel 1 (merged): GroupNorm partial sums for motion (blocks 0..511) and
// ref (blocks 512..575), deterministic two-stage.
// ---------------------------------------------------------------------------
__device__ void gn_body(const float* __restrict__ x, int per_sample, int nblk,
                        float* __restrict__ part, int bid) {
    int b   = bid / nblk;
    int blk = bid % nblk;
    const float* xb = x + (size_t)b * per_sample;
    int chunk = per_sample / nblk;
    int base  = blk * chunk;
    float s = 0.f, s2 = 0.f;
    for (int i = threadIdx.x * 4; i < chunk; i += 256 * 4) {
        float4 v = *(const float4*)(xb + base + i);
        s  += v.x + v.y + v.z + v.w;
        s2 += v.x * v.x + v.y * v.y + v.z * v.z + v.w * v.w;
    }
    #pragma unroll
    for (int off = 32; off; off >>= 1) {
        s  += __shfl_down(s, off);
        s2 += __shfl_down(s2, off);
    }
    __shared__ float red[8];
    int wid = threadIdx.x >> 6, lane = threadIdx.x & 63;
    if (lane == 0) { red[wid * 2] = s; red[wid * 2 + 1] = s2; }
    __syncthreads();
    if (threadIdx.x == 0) {
        for (int w = 1; w < 4; ++w) { s += red[w * 2]; s2 += red[w * 2 + 1]; }
        part[(size_t)(b * nblk + blk) * 2]     = s;
        part[(size_t)(b * nblk + blk) * 2 + 1] = s2;
    }
}
__global__ __launch_bounds__(256) void gn_all(const float* __restrict__ xm,
                                              const float* __restrict__ xr,
                                              float* __restrict__ part_m,
                                              float* __restrict__ part_r) {
    if (blockIdx.x < 512) gn_body(xm, NM_, NBM, part_m, blockIdx.x);
    else                  gn_body(xr, NR_, NBR, part_r, blockIdx.x - 512);
}

// ---------------------------------------------------------------------------
// Kernel 2 (merged): block 128 = GN finalize -> per (b,c) affine;
// blocks 0..127 = fp32->bf16 conversion of the four weight matrices.
// ---------------------------------------------------------------------------
__global__ __launch_bounds__(256) void fin_w2bf(const float* __restrict__ part_m,
                                                const float* __restrict__ part_r,
                                                const float* __restrict__ gamma,
                                                const float* __restrict__ beta,
                                                float* __restrict__ am, float* __restrict__ dm,
                                                float* __restrict__ ar, float* __restrict__ dr,
                                                const float* __restrict__ W0,
                                                const float* __restrict__ W1,
                                                const float* __restrict__ W2,
                                                const float* __restrict__ W3,
                                                u16* __restrict__ dst) {
    if (blockIdx.x == 128) {
        int c = threadIdx.x;
        float g = gamma[c], be = beta[c];
        for (int b = 0; b < B_; ++b) {
            float s = 0.f, s2 = 0.f;
            for (int i = 0; i < NBM; ++i) { s += part_m[(b * NBM + i) * 2]; s2 += part_m[(b * NBM + i) * 2 + 1]; }
            float mu   = s / (float)NM_;
            float var  = s2 / (float)NM_ - mu * mu;
            float rstd = rsqrtf(var + EPS_);
            am[b * C_ + c] = rstd * g;
            dm[b * C_ + c] = be - mu * rstd * g;

            s = 0.f; s2 = 0.f;
            for (int i = 0; i < NBR; ++i) { s += part_r[(b * NBR + i) * 2]; s2 += part_r[(b * NBR + i) * 2 + 1]; }
            mu   = s / (float)NR_;
            var  = s2 / (float)NR_ - mu * mu;
            rstd = rsqrtf(var + EPS_);
            ar[b * C_ + c] = rstd * g;
            dr[b * C_ + c] = be - mu * rstd * g;
        }
        return;
    }
    int idx = blockIdx.x * 256 + threadIdx.x;   // 32768 threads, 8 elems each
    int m = idx >> 13, off = (idx & 8191) * 8;
    const float* s = (m == 0 ? W0 : m == 1 ? W1 : m == 2 ? W2 : W3) + off;
    float4 a = *(const float4*)s, b = *(const float4*)(s + 4);
    ushort4 lo; lo.x = f2bf(a.x); lo.y = f2bf(a.y); lo.z = f2bf(a.z); lo.w = f2bf(a.w);
    ushort4 hi; hi.x = f2bf(b.x); hi.y = f2bf(b.y); hi.z = f2bf(b.z); hi.w = f2bf(b.w);
    *(ushort4*)(dst + m * 65536 + off)     = lo;
    *(ushort4*)(dst + m * 65536 + off + 4) = hi;
}

// ---------------------------------------------------------------------------
// Kernel 3 (merged): normalize fp32 [b][c][P] -> bf16 transposed [b][P][256]
// for motion (blocks 0..511) and ref (512..575). LDS transpose.
// ---------------------------------------------------------------------------
__device__ void norm_body(const float* __restrict__ X,
                          const float* __restrict__ alpha,
                          const float* __restrict__ delta,
                          u16* __restrict__ Y, int P, int px, int b,
                          u16* S) {
    int p0 = px * 64;
    int tid = threadIdx.x;
    #pragma unroll
    for (int pass = 0; pass < 4; ++pass) {
        int qi = pass * 256 + tid;
        int cq = qi & 63, pq = qi >> 6;
        float4 v[4];
        #pragma unroll
        for (int j = 0; j < 4; ++j) {
            int c = cq * 4 + j;
            v[j] = *(const float4*)(X + ((size_t)b * C_ + c) * P + p0 + pq * 4);
            float a = alpha[b * C_ + c], d = delta[b * C_ + c];
            v[j].x = v[j].x * a + d; v[j].y = v[j].y * a + d;
            v[j].z = v[j].z * a + d; v[j].w = v[j].w * a + d;
        }
        #pragma unroll
        for (int jj = 0; jj < 4; ++jj) {
            ushort4 o;
            o.x = f2bf(((const float*)&v[0])[jj]);
            o.y = f2bf(((const float*)&v[1])[jj]);
            o.z = f2bf(((const float*)&v[2])[jj]);
            o.w = f2bf(((const float*)&v[3])[jj]);
            *(ushort4*)&S[(pq * 4 + jj) * 256 + cq * 4] = o;
        }
    }
    __syncthreads();
    const char* Sb = (const char*)S;
    #pragma unroll
    for (int pass = 0; pass < 8; ++pass) {
        int i = pass * 256 + tid;
        int p = i >> 5, s = i & 31;
        uint4 d = *(const uint4*)(Sb + p * 512 + s * 16);
        *(uint4*)((char*)(Y + ((size_t)b * P + p0 + p) * C_) + s * 16) = d;
    }
}
__global__ __launch_bounds__(256) void norm_all(const float* __restrict__ xm,
                                                const float* __restrict__ xr,
                                                const float* __restrict__ am,
                                                const float* __restrict__ dm,
                                                const float* __restrict__ ar,
                                                const float* __restrict__ dr,
                                                u16* __restrict__ xnm,
                                                u16* __restrict__ xnr) {
    __shared__ __align__(16) u16 S[64 * 256];
    int bid = blockIdx.x;
    if (bid < 512) norm_body(xm, am, dm, xnm, PM_, bid & 127, bid >> 7, S);
    else { int i = bid - 512; norm_body(xr, ar, dr, xnr, PR_, i & 15, i >> 4, S); }
}

// ---------------------------------------------------------------------------
// 1x1 conv body, all-bf16 MFMA (16x16x32). X [b][P][256], W [256o][256c].
// Tile 64 o x 64 p, K=256 single-stage via global_load_lds (pre-swz source).
// OUT=0: u16 [b][p][o] (*oscale) | OUT=1: u16 [b][o][p] | OUT=2: f32 [b][o][p]+resid
// ---------------------------------------------------------------------------
template<int OUT>
__device__ void convA_body(char* lds,
                           const u16* __restrict__ Xb, const u16* __restrict__ Wb,
                           const float* __restrict__ bias, const float* __restrict__ resid,
                           void* __restrict__ Yv, int P, float oscale,
                           int px, int oy, int b) {
    int p0 = px * 64, o0 = oy * 64;
    int tid = threadIdx.x;
    int w = tid >> 6, l = tid & 63, lg = l >> 4, ln = l & 15;
    int wm = w >> 1, wn = w & 1;
    const char* Xg = (const char*)(Xb + ((size_t)b * P + p0) * C_);   // contiguous 32 KB
    const char* Wg = (const char*)(Wb + (size_t)o0 * C_);             // contiguous 32 KB
    #pragma unroll
    for (int i = 0; i < 8; ++i) {
        int ci = i * 4 + w;
        int d = ci * 1024 + l * 16;
        int srco = (d & ~511) | ((d & 511) ^ (((d >> 9) & 7) << 4));
        gl16(Xg + srco, lds + ci * 1024);
        gl16(Wg + srco, lds + 32768 + ci * 1024);
    }
    asm volatile("s_waitcnt vmcnt(0)" ::: "memory");
    __syncthreads();

    f32x4 acc[2][2];
    #pragma unroll
    for (int mm = 0; mm < 2; ++mm)
        #pragma unroll
        for (int nn = 0; nn < 2; ++nn) acc[mm][nn] = (f32x4)0.f;

    #pragma unroll
    for (int f = 0; f < 8; ++f) {
        short8 xf[2], wf[2];
        #pragma unroll
        for (int nn = 0; nn < 2; ++nn) {
            int p = wn * 32 + nn * 16 + ln;
            xf[nn] = lds8(lds + p * 512 + ((f * 64 + lg * 16) ^ ((p & 7) << 4)));
        }
        #pragma unroll
        for (int mm = 0; mm < 2; ++mm) {
            int o = wm * 32 + mm * 16 + ln;
            wf[mm] = lds8(lds + 32768 + o * 512 + ((f * 64 + lg * 16) ^ ((o & 7) << 4)));
        }
        #pragma unroll
        for (int mm = 0; mm < 2; ++mm)
            #pragma unroll
            for (int nn = 0; nn < 2; ++nn) {
                if (OUT == 1) acc[mm][nn] = mfma16(xf[nn], wf[mm], acc[mm][nn]); // D[m=p][n=o]
                else          acc[mm][nn] = mfma16(wf[mm], xf[nn], acc[mm][nn]); // D[m=o][n=p]
            }
    }
    __syncthreads();

    if constexpr (OUT == 0) {
        #pragma unroll
        for (int mm = 0; mm < 2; ++mm) {
            int obase = o0 + wm * 32 + mm * 16 + lg * 4;
            float b0 = bias[obase], b1 = bias[obase + 1], b2 = bias[obase + 2], b3 = bias[obase + 3];
            #pragma unroll
            for (int nn = 0; nn < 2; ++nn) {
                int pl = wn * 32 + nn * 16 + ln;
                int a = pl * 128 + ((wm * 64 + mm * 32 + lg * 8) ^ ((pl & 7) << 4));
                *(u32*)(lds + a)     = pk2bf((acc[mm][nn][0] + b0) * oscale, (acc[mm][nn][1] + b1) * oscale);
                *(u32*)(lds + a + 4) = pk2bf((acc[mm][nn][2] + b2) * oscale, (acc[mm][nn][3] + b3) * oscale);
            }
        }
        __syncthreads();
        u16* Y = (u16*)Yv;
        #pragma unroll
        for (int pass = 0; pass < 2; ++pass) {
            int i = pass * 256 + tid;
            int pl = i >> 3, s = i & 7;
            uint4 d = *(const uint4*)(lds + pl * 128 + ((s * 16) ^ ((pl & 7) << 4)));
            *(uint4*)(Y + (size_t)(b * P + p0 + pl) * C_ + o0 + s * 8) = d;
        }
    } else if constexpr (OUT == 1) {
        #pragma unroll
        for (int mm = 0; mm < 2; ++mm) {
            int ol = wm * 32 + mm * 16 + ln;
            float bo = bias[o0 + ol];
            #pragma unroll
            for (int nn = 0; nn < 2; ++nn) {
                int a = ol * 128 + ((wn * 64 + nn * 32 + lg * 8) ^ ((ol & 7) << 4));
                *(u32*)(lds + a)     = pk2bf(acc[mm][nn][0] + bo, acc[mm][nn][1] + bo);
                *(u32*)(lds + a + 4) = pk2bf(acc[mm][nn][2] + bo, acc[mm][nn][3] + bo);
            }
        }
        __syncthreads();
        u16* Y = (u16*)Yv;
        #pragma unroll
        for (int pass = 0; pass < 2; ++pass) {
            int i = pass * 256 + tid;
            int ol = i >> 3, s = i & 7;
            uint4 d = *(const uint4*)(lds + ol * 128 + ((s * 16) ^ ((ol & 7) << 4)));
            *(uint4*)(Y + (size_t)(b * C_ + o0 + ol) * P + p0 + s * 8) = d;
        }
    } else {
        #pragma unroll
        for (int mm = 0; mm < 2; ++mm) {
            int obase = wm * 32 + mm * 16 + lg * 4;
            #pragma unroll
            for (int r = 0; r < 4; ++r) {
                int ol = obase + r;
                float bo = bias[o0 + ol];
                #pragma unroll
                for (int nn = 0; nn < 2; ++nn) {
                    int a = ol * 256 + ((wn * 128 + nn * 64 + ln * 4) ^ ((ol & 7) << 4));
                    *(float*)(lds + a) = acc[mm][nn][r] + bo;
                }
            }
        }
        __syncthreads();
        float* Y = (float*)Yv;
        #pragma unroll
        for (int pass = 0; pass < 4; ++pass) {
            int i = pass * 256 + tid;
            int ol = i >> 4, s = i & 15;
            f32x4 dv = *(const f32x4*)(lds + ol * 256 + ((s * 16) ^ ((ol & 7) << 4)));
            size_t go = (size_t)(b * C_ + o0 + ol) * P + p0 + s * 4;
            float4 rv = *(const float4*)(resid + go);
            float4 o4;
            o4.x = dv[0] + rv.x; o4.y = dv[1] + rv.y; o4.z = dv[2] + rv.z; o4.w = dv[3] + rv.w;
            *(float4*)(Y + go) = o4;
        }
    }
}

// Kernel 4 (merged): q (blocks 0..2047), k (2048..2303), v (2304..2559)
__global__ __launch_bounds__(256) void convQKV(const u16* __restrict__ xnm,
                                               const u16* __restrict__ xnr,
                                               const u16* __restrict__ wall,
                                               const float* __restrict__ bq,
                                               const float* __restrict__ bk,
                                               const float* __restrict__ bv,
                                               u16* __restrict__ qT,
                                               u16* __restrict__ kT,
                                               u16* __restrict__ vh) {
    __shared__ __align__(16) char lds[65536];
    int bid = blockIdx.x;
    if (bid < 2048) {
        convA_body<0>(lds, xnm, wall, bq, nullptr, qT, PM_, QSCALE,
                      bid & 127, (bid >> 7) & 3, bid >> 9);
    } else if (bid < 2304) {
        int i = bid - 2048;
        convA_body<0>(lds, xnr, wall + 65536, bk, nullptr, kT, PR_, 1.f,
                      i & 15, (i >> 4) & 3, i >> 6);
    } else {
        int i = bid - 2304;
        convA_body<1>(lds, xnr, wall + 131072, bv, nullptr, vh, PR_, 1.f,
                      i & 15, (i >> 4) & 3, i >> 6);
    }
}

// Kernel 6: final conv, bf16 [b][p][c] in -> fp32 [b][c][p] + residual
__global__ __launch_bounds__(256) void convO(const u16* __restrict__ aoh,
                                             const u16* __restrict__ wall,
                                             const float* __restrict__ bo,
                                             const float* __restrict__ resid,
                                             float* __restrict__ out) {
    __shared__ __align__(16) char lds[65536];
    convA_body<2>(lds, aoh, wall + 196608, bo, resid, out, PM_, 1.f,
                  blockIdx.x, blockIdx.y, blockIdx.z);
}

// ---------------------------------------------------------------------------
// Kernel 5: flash cross-attention (R7-proven attn4, byte-identical math).
// Block = (b,t, 128 q), 4 waves x 32 q. KVBLK=64, grid 256 (1 block/CU).
// Only change vs R7: stage(0,0) issued BEFORE the Q-fragment loads so Q-load
// latency overlaps the first K/V staging (both async, independent).
// ---------------------------------------------------------------------------
__global__ __launch_bounds__(256, 1) void attn4(const u16* __restrict__ qT,  // [b][8192][256]
                                                const u16* __restrict__ kT,  // [b][1024][256]
                                                const u16* __restrict__ vh,  // [b][256][1024]
                                                u16* __restrict__ ao) {      // [b][8192][256]
    __shared__ __align__(16) char lds[147456]; // K dbuf 2x32K @0, V dbuf 2x32K @65536, P 4x4K @131072
    int b = blockIdx.z, t = blockIdx.y, q0 = blockIdx.x * 128;
    int tid = threadIdx.x, w = tid >> 6, l = tid & 63;
    int m31 = l & 31, hi = l >> 5;

    const char* Kb = (const char*)(kT + (size_t)b * PR_ * C_);
    const char* Vb = (const char*)(vh + (size_t)b * C_ * PR_);

    auto stage = [&](int buf, int kt) {
        char* Kl = lds + buf * 32768;
        char* Vl = lds + 65536 + buf * 32768;
        #pragma unroll
        for (int i = 0; i < 8; ++i) {            // K tile: contiguous 32KB, rows 512B
            int ci = i * 4 + w;
            int d = ci * 1024 + l * 16;
            int srco = (d & ~511) | ((d & 511) ^ (((d >> 9) & 7) << 4));
            gl16(Kb + (size_t)kt * 32768 + srco, Kl + ci * 1024);
        }
        #pragma unroll
        for (int i = 0; i < 8; ++i) {            // V tile: [256c][64k], rows 128B
            int ci = i * 4 + w;
            int d = ci * 1024 + l * 16;
            int c = d >> 7, s = (d >> 4) & 7;
            int srco = c * 2048 + kt * 128 + ((s * 16) ^ ((c & 7) << 4));
            gl16(Vb + srco, Vl + ci * 1024);
        }
    };

    stage(0, 0);                                 // issue first staging ASAP (async)

    // Q fragments (B operand), resident: lane holds Q[q=m31][c = ch*16 + 8*hi + e]
    // Loaded after stage-issue so Q-load latency overlaps the K/V staging.
    const char* Qrow = (const char*)(qT + ((size_t)b * PM_ + t * HW_ + q0 + w * 32 + m31) * C_);
    short8 qf[16];
    #pragma unroll
    for (int ch = 0; ch < 16; ++ch)
        qf[ch] = __builtin_bit_cast(short8, *(const uint4*)(Qrow + ch * 32 + hi * 16));

    f32x16 acc[8];
    #pragma unroll
    for (int cb = 0; cb < 8; ++cb) acc[cb] = (f32x16)0.f;
    float m_r = -1e30f, l_r = 0.f;

    asm volatile("s_waitcnt vmcnt(0)" ::: "memory");
    __syncthreads();

    char* Pw = lds + 131072 + w * 4096;          // per-wave P [32q][128B], swz (q&7)<<4
    int swzp = (m31 & 7) << 4;

    for (int kt = 0; kt < 16; ++kt) {
        int buf = kt & 1;
        if (kt < 15) stage(buf ^ 1, kt + 1);     // async prefetch overlaps compute
        const char* Kl = lds + buf * 32768;
        const char* Vl = lds + 65536 + buf * 32768;

        // ---- S^T = K · Q : rows k (0..63), cols q = m31 ----
        f32x16 s0 = (f32x16)0.f, s1 = (f32x16)0.f;
        #pragma unroll
        for (int ch = 0; ch < 16; ++ch) {
            int off = (ch * 32 + hi * 16) ^ swzp;
            short8 k0f = lds8(Kl + m31 * 512 + off);
            short8 k1f = lds8(Kl + (32 + m31) * 512 + off);
            s0 = mfma32(k0f, qf[ch], s0);
            s1 = mfma32(k1f, qf[ch], s1);
        }

        // ---- online softmax (defer-max THR=8; exp2) ----
        float tm = -1e30f;
        #pragma unroll
        for (int e = 0; e < 16; ++e) tm = fmaxf(tm, fmaxf(s0[e], s1[e]));
        if (__any(tm > m_r + 8.f)) {             // fires on tile 0, then rarely
            float tmax = fmaxf(tm, __shfl_xor(tm, 32));
            float mn = fmaxf(m_r, tmax);
            float sc = __builtin_amdgcn_exp2f(m_r - mn);
            l_r *= sc;
            #pragma unroll
            for (int cb = 0; cb < 8; ++cb)
                #pragma unroll
                for (int e = 0; e < 16; ++e) acc[cb][e] *= sc;
            m_r = mn;
        }
        float p0[16], p1[16], rs = 0.f;
        #pragma unroll
        for (int e = 0; e < 16; ++e) { p0[e] = __builtin_amdgcn_exp2f(s0[e] - m_r); rs += p0[e]; }
        #pragma unroll
        for (int e = 0; e < 16; ++e) { p1[e] = __builtin_amdgcn_exp2f(s1[e] - m_r); rs += p1[e]; }
        l_r += rs;                                // per-lane partial; reduced once at end

        // ---- publish P: row q=m31, key0 = 8a + 4hi, e-block = 4*(a&3) ----
        #pragma unroll
        for (int a = 0; a < 8; ++a) {
            const float* parr = (a < 4) ? p0 : p1;
            int eb = (a & 3) * 4;
            uint2 d;
            d.x = pk2bf(parr[eb + 0], parr[eb + 1]);
            d.y = pk2bf(parr[eb + 2], parr[eb + 3]);
            *(uint2*)(Pw + m31 * 128 + ((a * 16 + hi * 8) ^ swzp)) = d;
        }

        // ---- PV B-fragments: one b128 per 16-key chunk from own q-row ----
        short8 bP[4];
        #pragma unroll
        for (int kc = 0; kc < 4; ++kc)
            bP[kc] = lds8(Pw + m31 * 128 + ((kc * 32 + hi * 16) ^ swzp));

        // ---- O^T += V^T · P : rows c, cols q = m31 ----
        #pragma unroll
        for (int cb = 0; cb < 8; ++cb) {
            int c = cb * 32 + m31;
            int rowb = c * 128, swzc = (c & 7) << 4;
            #pragma unroll
            for (int kc = 0; kc < 4; ++kc) {
                short8 vf = lds8(Vl + rowb + ((kc * 32 + hi * 16) ^ swzc));
                acc[cb] = mfma32(vf, bP[kc], acc[cb]);
            }
        }

        asm volatile("s_waitcnt vmcnt(0)" ::: "memory");
        __syncthreads();
    }

    // ---- epilogue: reduce l across k-halves, normalize, stage [128q][256c] ----
    l_r += __shfl_xor(l_r, 32);
    float invl = 1.f / l_r;
    char* Os = lds;                               // 64 KB staging (post-barrier reuse)
    int q = w * 32 + m31;
    int swzq = (q & 7) << 4;
    #pragma unroll
    for (int cb = 0; cb < 8; ++cb)
        #pragma unroll
        for (int m = 0; m < 4; ++m) {
            uint2 d;
            d.x = pk2bf(acc[cb][4 * m + 0] * invl, acc[cb][4 * m + 1] * invl);
            d.y = pk2bf(acc[cb][4 * m + 2] * invl, acc[cb][4 * m + 3] * invl);
            *(uint2*)(Os + q * 512 + ((cb * 64 + m * 16 + hi * 8) ^ swzq)) = d;
        }
    __syncthreads();
    u16* aob = ao + ((size_t)b * PM_ + t * HW_ + q0) * C_;
    // 128 q rows x 512 B = 64 KB -> 16 passes
    #pragma unroll
    for (int pass = 0; pass < 16; ++pass) {
        int i = pass * 256 + tid;
        int qr = i >> 5, s = i & 31;
        uint4 d = *(const uint4*)(Os + qr * 512 + ((s * 16) ^ ((qr & 7) << 4)));
        *(uint4*)((char*)(aob + (size_t)qr * C_) + s * 16) = d;
    }
}

// ---------------------------------------------------------------------------
// Launcher. ws bytes:
//   0 part_m | 4096 part_r | 8192 am | 12288 dm | 16384 ar | 20480 dr
//   32768   Wbf 4x128KB (q,k,v,o)
//   1 MB    xnm bf16 [4][8192][256] (16 MB)  -- ALIASED with ao
//   17 MB   xnr (2 MB) | 19 MB qT (16 MB) | 35 MB kT (2 MB) | 37 MB vh (2 MB)
// ---------------------------------------------------------------------------
extern "C" void kernel_launch(void* const* d_in, const int* in_sizes, int n_in,
                              void* d_out, int out_size, void* d_ws, size_t ws_size,
                              hipStream_t stream) {
    const float* x_motion = (const float*)d_in[0];
    const float* x_ref    = (const float*)d_in[1];
    const float* gamma    = (const float*)d_in[2];
    const float* beta     = (const float*)d_in[3];
    const float* Wq = (const float*)d_in[4];
    const float* bq = (const float*)d_in[5];
    const float* Wk = (const float*)d_in[6];
    const float* bk = (const float*)d_in[7];
    const float* Wv = (const float*)d_in[8];
    const float* bv = (const float*)d_in[9];
    const float* Wo = (const float*)d_in[10];
    const float* bo = (const float*)d_in[11];
    float* out = (float*)d_out;
    char* base = (char*)d_ws;

    float* part_m = (float*)(base);
    float* part_r = (float*)(base + 4096);
    float* am = (float*)(base + 8192);
    float* dm = (float*)(base + 12288);
    float* ar = (float*)(base + 16384);
    float* dr = (float*)(base + 20480);
    u16* wall = (u16*)(base + 32768);
    u16* xnm = (u16*)(base + 1048576);                             // 16 MB
    u16* aoh = xnm;                                                // alias (xnm dead after convQKV)
    u16* xnr = (u16*)(base + 1048576 + 16777216);                  // 2 MB
    u16* qT  = (u16*)(base + 1048576 + 16777216 + 2097152);        // 16 MB
    u16* kTp = (u16*)(base + 1048576 + 2 * 16777216 + 2097152);    // 2 MB
    u16* vh  = (u16*)(base + 1048576 + 2 * 16777216 + 2 * 2097152);// 2 MB

    gn_all<<<dim3(576), 256, 0, stream>>>(x_motion, x_ref, part_m, part_r);
    fin_w2bf<<<dim3(129), 256, 0, stream>>>(part_m, part_r, gamma, beta,
                                            am, dm, ar, dr, Wq, Wk, Wv, Wo, wall);
    norm_all<<<dim3(576), 256, 0, stream>>>(x_motion, x_ref, am, dm, ar, dr, xnm, xnr);
    convQKV<<<dim3(2560), 256, 0, stream>>>(xnm, xnr, wall, bq, bk, bv, qT, kTp, vh);
    attn4<<<dim3(8, T_, B_), 256, 0, stream>>>(qT, kTp, vh, aoh);
    convO<<<dim3(PM_ / 64, 4, B_), 256, 0, stream>>>(aoh, wall, bo, x_motion, out);
}